// Round 3
// baseline (1019.291 us; speedup 1.0000x reference)
//
#include <hip/hip_runtime.h>
#include <hip/hip_bf16.h>

#define CDIM 256
#define NH 8
#define HDIM 32

typedef short bf8 __attribute__((ext_vector_type(8)));
typedef float f32x4 __attribute__((ext_vector_type(4)));

__device__ __forceinline__ float bf2f(ushort u) {
  union { unsigned int i; float f; } x; x.i = ((unsigned int)u) << 16; return x.f;
}
__device__ __forceinline__ ushort f2bf(float f) {
  union { float f; unsigned int i; } x; x.f = f;
  unsigned int lsb = (x.i >> 16) & 1u;
  unsigned int r = x.i + 0x7fffu + lsb;
  return (ushort)(r >> 16);
}

// fast gelu (tanh form): max err ~2e-4 at |t|<1.5 where our pre-acts live
// (sigma~0.32); dominated by the bf16 rounding of the hidden layer anyway.
__device__ __forceinline__ float fast_gelu(float t) {
  float u = 0.7978845608028654f * (t + 0.044715f * t * t * t);
  float ez = __expf(2.f * u);
  float th = 1.f - 2.f * __builtin_amdgcn_rcpf(ez + 1.f);
  return 0.5f * t * (1.f + th);
}

// ---------------- casts fp32 -> bf16 (vectorized) ----------------
__global__ void k_cast4(const float4* __restrict__ s, ushort4* __restrict__ d, int n4) {
  int i = blockIdx.x * blockDim.x + threadIdx.x;
  if (i < n4) {
    float4 v = s[i];
    ushort4 o;
    o.x = f2bf(v.x); o.y = f2bf(v.y); o.z = f2bf(v.z); o.w = f2bf(v.w);
    d[i] = o;
  }
}

// ---------------- CSR build ----------------
__global__ void k_hist(const int* __restrict__ dst, int E, int* __restrict__ deg) {
  int i = blockIdx.x * blockDim.x + threadIdx.x;
  if (i < E) atomicAdd(&deg[dst[i]], 1);
}

__global__ __launch_bounds__(1024) void k_scan1(const int* __restrict__ deg, int N,
                                                int* __restrict__ rowptr, int* __restrict__ bsum) {
  __shared__ int s[1024];
  int t = threadIdx.x;
  int i = blockIdx.x * 1024 + t;
  int val = (i < N) ? deg[i] : 0;
  s[t] = val;
  __syncthreads();
  for (int off = 1; off < 1024; off <<= 1) {
    int add = (t >= off) ? s[t - off] : 0;
    __syncthreads();
    s[t] += add;
    __syncthreads();
  }
  if (i < N) rowptr[i + 1] = s[t];
  if (t == 1023) bsum[blockIdx.x] = s[t];
}

__global__ void k_scan2(int* __restrict__ bsum, int nb) {
  if (threadIdx.x == 0 && blockIdx.x == 0) {
    int run = 0;
    for (int j = 0; j < nb; ++j) { int t = bsum[j]; bsum[j] = run; run += t; }
  }
}

__global__ void k_scan3(int* __restrict__ rowptr, const int* __restrict__ bsum, int N) {
  int i = blockIdx.x * blockDim.x + threadIdx.x;
  if (i < N) rowptr[i + 1] += bsum[i >> 10];
  if (i == 0) rowptr[0] = 0;
}

__global__ void k_scatter(const int* __restrict__ src, const int* __restrict__ dst, int E,
                          const int* __restrict__ rowptr, int* __restrict__ cur,
                          int* __restrict__ csr_src) {
  int i = blockIdx.x * blockDim.x + threadIdx.x;
  if (i < E) {
    int d = dst[i];
    int pos = rowptr[d] + atomicAdd(&cur[d], 1);
    csr_src[pos] = src[i];
  }
}

// ---------------- 64x64-per-wave GEMM tile (bf16 MFMA 16x16x32) ----------------
// A row-major bf16 [nrows x lda], row-clamped; B = W [out,in] row-major bf16 (acts as B^T).
// acc[ri*4+cj]: C rows row0+ri*16+quad*4+i, cols col0+cj*16+m.
__device__ __forceinline__ void wave_tile64(const ushort* __restrict__ A, int lda, int row0, int nrows,
                                            const ushort* __restrict__ B, int ldb, int col0,
                                            int K, f32x4* acc) {
  int lane = threadIdx.x & 63;
  int m = lane & 15, quad = lane >> 4;
  const ushort* ap[4];
  const ushort* bp[4];
#pragma unroll
  for (int ri = 0; ri < 4; ++ri) {
    int r = row0 + ri * 16 + m;
    r = (r < nrows) ? r : (nrows - 1);
    ap[ri] = A + (size_t)r * lda + quad * 8;
  }
#pragma unroll
  for (int cj = 0; cj < 4; ++cj)
    bp[cj] = B + (size_t)(col0 + cj * 16 + m) * ldb + quad * 8;
  for (int k0 = 0; k0 < K; k0 += 32) {
    bf8 a[4], b[4];
#pragma unroll
    for (int ri = 0; ri < 4; ++ri) a[ri] = *(const bf8*)(ap[ri] + k0);
#pragma unroll
    for (int cj = 0; cj < 4; ++cj) b[cj] = *(const bf8*)(bp[cj] + k0);
#pragma unroll
    for (int ri = 0; ri < 4; ++ri)
#pragma unroll
      for (int cj = 0; cj < 4; ++cj)
        acc[ri * 4 + cj] = __builtin_amdgcn_mfma_f32_16x16x32_bf16(a[ri], b[cj], acc[ri * 4 + cj], 0, 0, 0);
  }
}

// q,k,v = feat @ W{q,k,v}^T + b ; block = 64 rows x 256 cols of one of q/k/v
__global__ __launch_bounds__(256) void k_qkv(const ushort* __restrict__ featb,
                                             const ushort* __restrict__ Wq, const ushort* __restrict__ Wk,
                                             const ushort* __restrict__ Wv,
                                             const float* __restrict__ bq, const float* __restrict__ bk,
                                             const float* __restrict__ bv,
                                             ushort* __restrict__ q, ushort* __restrict__ k,
                                             ushort* __restrict__ v, int N) {
  int rt = blockIdx.x, which = blockIdx.y;
  const ushort* W = (which == 0) ? Wq : (which == 1) ? Wk : Wv;
  const float* bias = (which == 0) ? bq : (which == 1) ? bk : bv;
  ushort* outp = (which == 0) ? q : (which == 1) ? k : v;
  int wave = threadIdx.x >> 6, lane = threadIdx.x & 63, m = lane & 15, quad = lane >> 4;
  int row0 = rt * 64, col0 = wave * 64;

  f32x4 acc[16];
#pragma unroll
  for (int j = 0; j < 16; ++j) acc[j] = (f32x4){0.f, 0.f, 0.f, 0.f};
  wave_tile64(featb, CDIM, row0, N, W, CDIM, col0, CDIM, acc);

#pragma unroll
  for (int cj = 0; cj < 4; ++cj) {
    int cc = col0 + cj * 16 + m;
    float bs = bias[cc];
#pragma unroll
    for (int ri = 0; ri < 4; ++ri)
#pragma unroll
      for (int i = 0; i < 4; ++i) {
        int r = row0 + ri * 16 + quad * 4 + i;
        if (r < N) outp[(size_t)r * CDIM + cc] = f2bf(acc[ri * 4 + cj][i] + bs);
      }
  }
}

// fused segment softmax + aggregate: one block (256 thr) per dst node, two-phase, no shfl chains.
__global__ __launch_bounds__(256) void k_edge_agg(const ushort* __restrict__ q,
                                                  const ushort* __restrict__ kk,
                                                  const ushort* __restrict__ vv,
                                                  const int* __restrict__ rowptr,
                                                  const int* __restrict__ csr_src,
                                                  int N,
                                                  ushort* __restrict__ wv) {
  __shared__ float e_T[8 * 36];   // [head][36] padded, 16B-aligned groups of 4
  __shared__ int srcs[32];
  __shared__ float wdens[32];

  int n = blockIdx.x;
  int t = threadIdx.x;
  int lane = t & 63, wave = t >> 6;
  int el = t >> 3, h = t & 7;      // phase-A role: edge-slot, head
  int h2 = t >> 5;                  // phase-B role: head of channel t

  int beg = rowptr[n], end = rowptr[n + 1];
  int deg = end - beg;

  // q slice for (this thread's head) into registers, f32
  float qf[32];
  {
    const ushort* qp = q + (size_t)n * CDIM + h * HDIM;
#pragma unroll
    for (int g = 0; g < 4; ++g) {
      bf8 qv = *(const bf8*)(qp + g * 8);
#pragma unroll
      for (int j = 0; j < 8; ++j) qf[g * 8 + j] = bf2f((ushort)qv[j]);
    }
  }

  float accv = 0.f;      // phase-B accumulator for channel t
  float den_part = 0.f;  // phase-A partial denominator for (el,h)

  int nch = (deg + 31) >> 5;
  for (int ch = 0; ch < nch; ++ch) {
    int eidx = beg + ch * 32 + el;
    int src = 0;
    float e = 0.f;
    if (eidx < end) {
      src = csr_src[eidx];
      const ushort* kp = kk + (size_t)src * CDIM + h * HDIM;
      float dot = 0.f;
#pragma unroll
      for (int g = 0; g < 4; ++g) {
        bf8 kv = *(const bf8*)(kp + g * 8);
#pragma unroll
        for (int j = 0; j < 8; ++j) dot = fmaf(qf[g * 8 + j], bf2f((ushort)kv[j]), dot);
      }
      float s = dot * 0.17677669529663687f;  // 1/sqrt(32)
      s = fminf(10.f, fmaxf(-10.f, s));
      e = __expf(s - 10.f);  // fixed shift: softmax shift-invariant, scores clamped
    }
    e_T[h * 36 + el] = e;
    if (h == 0) srcs[el] = src;
    den_part += e;
    __syncthreads();

    // phase B: channel-parallel aggregate of these 32 edges
#pragma unroll
    for (int g4 = 0; g4 < 8; ++g4) {
      int4 s4 = *(const int4*)&srcs[g4 * 4];
      float4 e4 = *(const float4*)&e_T[h2 * 36 + g4 * 4];
      accv = fmaf(e4.x, bf2f(vv[(size_t)s4.x * CDIM + t]), accv);
      accv = fmaf(e4.y, bf2f(vv[(size_t)s4.y * CDIM + t]), accv);
      accv = fmaf(e4.z, bf2f(vv[(size_t)s4.z * CDIM + t]), accv);
      accv = fmaf(e4.w, bf2f(vv[(size_t)s4.w * CDIM + t]), accv);
    }
    __syncthreads();
  }

  // denominator: reduce den_part over el (lanes with equal lane&7, then across waves)
  float d = den_part;
  d += __shfl_xor(d, 8);
  d += __shfl_xor(d, 16);
  d += __shfl_xor(d, 32);
  if (lane < 8) wdens[wave * 8 + lane] = d;
  __syncthreads();
  float den = wdens[h2] + wdens[8 + h2] + wdens[16 + h2] + wdens[24 + h2];
  wv[(size_t)n * CDIM + t] = f2bf((deg > 0) ? accv / den : 0.f);
}

// x = feat + wv @ Wp^T + bp  (fp32 out); block = 64 rows x 256 cols
__global__ __launch_bounds__(256) void k_proj(const ushort* __restrict__ wv,
                                              const ushort* __restrict__ Wp,
                                              const float* __restrict__ bp,
                                              const float* __restrict__ feat,
                                              float* __restrict__ x, int N) {
  int rt = blockIdx.x;
  int wave = threadIdx.x >> 6, lane = threadIdx.x & 63, m = lane & 15, quad = lane >> 4;
  int row0 = rt * 64, col0 = wave * 64;
  f32x4 acc[16];
#pragma unroll
  for (int j = 0; j < 16; ++j) acc[j] = (f32x4){0.f, 0.f, 0.f, 0.f};
  wave_tile64(wv, CDIM, row0, N, Wp, CDIM, col0, CDIM, acc);
#pragma unroll
  for (int cj = 0; cj < 4; ++cj) {
    int cc = col0 + cj * 16 + m;
    float bs = bp[cc];
#pragma unroll
    for (int ri = 0; ri < 4; ++ri)
#pragma unroll
      for (int i = 0; i < 4; ++i) {
        int r = row0 + ri * 16 + quad * 4 + i;
        if (r < N) x[(size_t)r * CDIM + cc] = acc[ri * 4 + cj][i] + bs + feat[(size_t)r * CDIM + cc];
      }
  }
}

// h = layernorm(x)*g + b -> bf16 ; one wave per row
__global__ __launch_bounds__(256) void k_ln(const float* __restrict__ x,
                                            const float* __restrict__ g,
                                            const float* __restrict__ b,
                                            ushort* __restrict__ h) {
  int row = blockIdx.x * 4 + (threadIdx.x >> 6);
  int lane = threadIdx.x & 63;
  const float* xr = x + (size_t)row * CDIM;
  float4 xv = *(const float4*)(xr + lane * 4);
  float s = xv.x + xv.y + xv.z + xv.w;
  float ss = xv.x * xv.x + xv.y * xv.y + xv.z * xv.z + xv.w * xv.w;
#pragma unroll
  for (int msk = 1; msk <= 32; msk <<= 1) {
    s += __shfl_xor(s, msk);
    ss += __shfl_xor(ss, msk);
  }
  float mu = s * (1.f / CDIM);
  float var = ss * (1.f / CDIM) - mu * mu;
  float rs = rsqrtf(var + 1e-5f);
  float xe[4] = {xv.x, xv.y, xv.z, xv.w};
#pragma unroll
  for (int t = 0; t < 4; ++t) {
    int cc = lane * 4 + t;
    h[(size_t)row * CDIM + cc] = f2bf((xe[t] - mu) * rs * g[cc] + b[cc]);
  }
}

// fused MLP: out = x + gelu(h@W1^T+b1)@W2^T + b2. Block = 32 rows.
// Hidden (1024) in 4 chunks of 256. Software-pipelined: the merged k-loop
// computes phase2(chunk c) from LDS *and* phase1(chunk c+1) from global in the
// same body — two independent dep chains so a load stall in one is hidden by
// the other's MFMAs (in-wave ILP; occupancy was shown NOT to be the lever, r2).
// gelu via tanh-form (exp+rcp) instead of erff: VALU burst between barriers.
__global__ __launch_bounds__(256) void k_mlp(const ushort* __restrict__ h,
                                             const ushort* __restrict__ W1,
                                             const float* __restrict__ b1,
                                             const ushort* __restrict__ W2,
                                             const float* __restrict__ b2,
                                             const float* __restrict__ x,
                                             float* __restrict__ out, int N) {
  __shared__ ushort sh[32 * 256];  // 16 KB
  int rt = blockIdx.x;
  int row0 = rt * 32;
  int wave = threadIdx.x >> 6, lane = threadIdx.x & 63, m = lane & 15, quad = lane >> 4;

  // A (h rows) fragment pointers, row-clamped
  const ushort* ap[2];
#pragma unroll
  for (int ri = 0; ri < 2; ++ri) {
    int r = row0 + ri * 16 + m;
    r = (r < N) ? r : (N - 1);
    ap[ri] = h + (size_t)r * CDIM + quad * 8;
  }
  // W1 fragment pointers at chunk-local col (chunk base added as c*65536)
  const ushort* bp1[4];
#pragma unroll
  for (int cj = 0; cj < 4; ++cj)
    bp1[cj] = W1 + (size_t)(wave * 64 + cj * 16 + m) * CDIM + quad * 8;
  // W2 fragment pointers (out col = wave*64 + cj*16 + m), K dim 1024
  const ushort* bp2[4];
#pragma unroll
  for (int cj = 0; cj < 4; ++cj)
    bp2[cj] = W2 + (size_t)(wave * 64 + cj * 16 + m) * 1024 + quad * 8;

  f32x4 acc2[8];   // persistent output accumulator
  f32x4 acch[8];   // hidden-chunk accumulator
#pragma unroll
  for (int j = 0; j < 8; ++j) {
    acc2[j] = (f32x4){0.f, 0.f, 0.f, 0.f};
    acch[j] = (f32x4){0.f, 0.f, 0.f, 0.f};
  }

  // prologue: phase1 of chunk 0
#pragma unroll
  for (int k0 = 0; k0 < 256; k0 += 32) {
    bf8 a[2], b[4];
#pragma unroll
    for (int ri = 0; ri < 2; ++ri) a[ri] = *(const bf8*)(ap[ri] + k0);
#pragma unroll
    for (int cj = 0; cj < 4; ++cj) b[cj] = *(const bf8*)(bp1[cj] + k0);
#pragma unroll
    for (int ri = 0; ri < 2; ++ri)
#pragma unroll
      for (int cj = 0; cj < 4; ++cj)
        acch[ri * 4 + cj] = __builtin_amdgcn_mfma_f32_16x16x32_bf16(a[ri], b[cj], acch[ri * 4 + cj], 0, 0, 0);
  }

  for (int c = 0; c < 4; ++c) {
    if (c) __syncthreads();  // prior chunk's phase-2 LDS reads done before overwrite
    // gelu(acch + b1) -> swizzled LDS
#pragma unroll
    for (int cj = 0; cj < 4; ++cj) {
      int ccl = wave * 64 + cj * 16 + m;       // chunk-local hidden col
      float bs = b1[c * 256 + ccl];
#pragma unroll
      for (int ri = 0; ri < 2; ++ri)
#pragma unroll
        for (int i = 0; i < 4; ++i) {
          int lr = ri * 16 + quad * 4 + i;
          float tt = acch[ri * 4 + cj][i] + bs;
          float gl = fast_gelu(tt);
          int sc = ((((ccl >> 3) ^ (lr & 7)) << 3) | (ccl & 7));
          sh[lr * 256 + sc] = f2bf(gl);
        }
    }
    __syncthreads();

    bool nxt = (c < 3);
    if (nxt) {
#pragma unroll
      for (int j = 0; j < 8; ++j) acch[j] = (f32x4){0.f, 0.f, 0.f, 0.f};
    }

    // merged loop: phase2(c) from LDS + phase1(c+1) from global
#pragma unroll
    for (int k0 = 0; k0 < 256; k0 += 32) {
      int g = (k0 >> 3) + quad;
      bf8 a2[2], b2v[4];
#pragma unroll
      for (int ri = 0; ri < 2; ++ri) {
        int lr = ri * 16 + m;
        a2[ri] = *(const bf8*)&sh[lr * 256 + ((g ^ (lr & 7)) << 3)];
      }
#pragma unroll
      for (int cj = 0; cj < 4; ++cj) b2v[cj] = *(const bf8*)(bp2[cj] + c * 256 + k0);
#pragma unroll
      for (int ri = 0; ri < 2; ++ri)
#pragma unroll
        for (int cj = 0; cj < 4; ++cj)
          acc2[ri * 4 + cj] = __builtin_amdgcn_mfma_f32_16x16x32_bf16(a2[ri], b2v[cj], acc2[ri * 4 + cj], 0, 0, 0);

      if (nxt) {
        bf8 a1[2], b1v[4];
#pragma unroll
        for (int ri = 0; ri < 2; ++ri) a1[ri] = *(const bf8*)(ap[ri] + k0);
#pragma unroll
        for (int cj = 0; cj < 4; ++cj) b1v[cj] = *(const bf8*)(bp1[cj] + (c + 1) * 65536 + k0);
#pragma unroll
        for (int ri = 0; ri < 2; ++ri)
#pragma unroll
          for (int cj = 0; cj < 4; ++cj)
            acch[ri * 4 + cj] = __builtin_amdgcn_mfma_f32_16x16x32_bf16(a1[ri], b1v[cj], acch[ri * 4 + cj], 0, 0, 0);
      }
    }
  }

#pragma unroll
  for (int cj = 0; cj < 4; ++cj) {
    int cc = wave * 64 + cj * 16 + m;
    float bs = b2[cc];
#pragma unroll
    for (int ri = 0; ri < 2; ++ri)
#pragma unroll
      for (int i = 0; i < 4; ++i) {
        int r = row0 + ri * 16 + quad * 4 + i;
        if (r < N) out[(size_t)r * CDIM + cc] = x[(size_t)r * CDIM + cc] + acc2[ri * 4 + cj][i] + bs;
      }
  }
}

extern "C" void kernel_launch(void* const* d_in, const int* in_sizes, int n_in,
                              void* d_out, int out_size, void* d_ws, size_t ws_size,
                              hipStream_t stream) {
  const float* feat = (const float*)d_in[0];
  const int* esrc = (const int*)d_in[1];
  const int* edst = (const int*)d_in[2];
  const float* Wq = (const float*)d_in[3];
  const float* bq = (const float*)d_in[4];
  const float* Wk = (const float*)d_in[5];
  const float* bk = (const float*)d_in[6];
  const float* Wv = (const float*)d_in[7];
  const float* bv = (const float*)d_in[8];
  const float* Wp = (const float*)d_in[9];
  const float* bp = (const float*)d_in[10];
  const float* lng = (const float*)d_in[11];
  const float* lnb = (const float*)d_in[12];
  const float* W1 = (const float*)d_in[13];
  const float* b1 = (const float*)d_in[14];
  const float* W2 = (const float*)d_in[15];
  const float* b2 = (const float*)d_in[16];

  const int N = in_sizes[0] / CDIM;  // 50000
  const int E = in_sizes[1];         // 1600000
  const size_t NC2 = (size_t)N * CDIM * 2;  // bf16 plane: 25.6 MB

  // Workspace (~112 MB, lifetime overlays):
  //   [0,NC2) q | x(f32,2*NC2) overlays q+k from proj on
  //   [NC2,2NC2) k
  //   [2NC2,3NC2) v | h(bf16) overlays v from ln on
  //   [3NC2,4NC2) wv | featb(bf16) overlays (dead before edge_agg writes wv)
  //   [4NC2,..) CSR, then bf16 weights
  char* w = (char*)d_ws;
  ushort* q   = (ushort*)(w);
  ushort* kk  = (ushort*)(w + NC2);
  ushort* vv  = (ushort*)(w + 2 * NC2);
  ushort* wvb = (ushort*)(w + 3 * NC2);
  ushort* featb = (ushort*)(w + 3 * NC2);  // overlays wv (disjoint lifetime)
  float*  x   = (float*)(w);               // overlays q+k
  ushort* h   = (ushort*)(w + 2 * NC2);    // overlays v

  char* csr = w + 4 * NC2;
  int* rowptr  = (int*)(csr);
  int* deg     = (int*)(csr + 200064);
  int* csr_src = (int*)(csr + 400128);
  int* bsum    = (int*)(csr + 400128 + (size_t)E * 4);

  char* wb = csr + 400128 + (size_t)E * 4 + 256;
  ushort* Wqb = (ushort*)(wb);
  ushort* Wkb = (ushort*)(wb + 131072);
  ushort* Wvb = (ushort*)(wb + 262144);
  ushort* Wpb = (ushort*)(wb + 393216);
  ushort* W1b = (ushort*)(wb + 524288);
  ushort* W2b = (ushort*)(wb + 1048576);

  const int nb = (N + 1023) / 1024;
  const int RT64 = (N + 63) / 64;   // 782
  const int RT32 = (N + 31) / 32;   // 1563

  // weight + feat casts
  k_cast4<<<(16384 + 255) / 256, 256, 0, stream>>>((const float4*)Wq, (ushort4*)Wqb, 16384);
  k_cast4<<<(16384 + 255) / 256, 256, 0, stream>>>((const float4*)Wk, (ushort4*)Wkb, 16384);
  k_cast4<<<(16384 + 255) / 256, 256, 0, stream>>>((const float4*)Wv, (ushort4*)Wvb, 16384);
  k_cast4<<<(16384 + 255) / 256, 256, 0, stream>>>((const float4*)Wp, (ushort4*)Wpb, 16384);
  k_cast4<<<(65536 + 255) / 256, 256, 0, stream>>>((const float4*)W1, (ushort4*)W1b, 65536);
  k_cast4<<<(65536 + 255) / 256, 256, 0, stream>>>((const float4*)W2, (ushort4*)W2b, 65536);
  {
    int n4 = N * CDIM / 4;
    k_cast4<<<(n4 + 255) / 256, 256, 0, stream>>>((const float4*)feat, (ushort4*)featb, n4);
  }

  // CSR build (group edges by dst)
  hipMemsetAsync(deg, 0, (size_t)N * 4, stream);
  k_hist<<<(E + 255) / 256, 256, 0, stream>>>(edst, E, deg);
  k_scan1<<<nb, 1024, 0, stream>>>(deg, N, rowptr, bsum);
  k_scan2<<<1, 64, 0, stream>>>(bsum, nb);
  k_scan3<<<(N + 255) / 256, 256, 0, stream>>>(rowptr, bsum, N);
  hipMemsetAsync(deg, 0, (size_t)N * 4, stream);
  k_scatter<<<(E + 255) / 256, 256, 0, stream>>>(esrc, edst, E, rowptr, deg, csr_src);

  // QKV projections (featb dead after this; wv region then reusable)
  k_qkv<<<dim3(RT64, 3), 256, 0, stream>>>(featb, Wqb, Wkb, Wvb, bq, bk, bv, q, kk, vv, N);
  // fused segment-softmax + aggregate
  k_edge_agg<<<N, 256, 0, stream>>>(q, kk, vv, rowptr, csr_src, N, wvb);
  // x = feat + wv@Wp^T + bp
  k_proj<<<RT64, 256, 0, stream>>>(wvb, Wpb, bp, feat, x, N);
  // h = LN(x)
  k_ln<<<N / 4, 256, 0, stream>>>(x, lng, lnb, h);
  // out = x + gelu(h@W1^T+b1)@W2^T + b2 (fused through LDS, pipelined chunks)
  k_mlp<<<RT32, 256, 0, stream>>>(h, W1b, b1, W2b, b2, x, (float*)d_out, N);
}

// Round 5
// 953.606 us; speedup vs baseline: 1.0689x; 1.0689x over previous
//
#include <hip/hip_runtime.h>
#include <hip/hip_bf16.h>

#define CDIM 256
#define NH 8
#define HDIM 32

typedef short bf8 __attribute__((ext_vector_type(8)));
typedef float f32x4 __attribute__((ext_vector_type(4)));

__device__ __forceinline__ float bf2f(ushort u) {
  union { unsigned int i; float f; } x; x.i = ((unsigned int)u) << 16; return x.f;
}
__device__ __forceinline__ ushort f2bf(float f) {
  union { float f; unsigned int i; } x; x.f = f;
  unsigned int lsb = (x.i >> 16) & 1u;
  unsigned int r = x.i + 0x7fffu + lsb;
  return (ushort)(r >> 16);
}

// fast gelu (tanh form): max err ~2e-4 where pre-acts live (sigma~0.32).
__device__ __forceinline__ float fast_gelu(float t) {
  float u = 0.7978845608028654f * (t + 0.044715f * t * t * t);
  float ez = __expf(2.f * u);
  float th = 1.f - 2.f * __builtin_amdgcn_rcpf(ez + 1.f);
  return 0.5f * t * (1.f + th);
}

// async global->LDS, 16B per lane; LDS dest = wave-uniform base + lane*16.
__device__ __forceinline__ void gload_lds16(const ushort* g, ushort* l) {
  __builtin_amdgcn_global_load_lds((const __attribute__((address_space(1))) unsigned int*)g,
                                   (__attribute__((address_space(3))) unsigned int*)l,
                                   16, 0, 0);
}

// ---------------- casts fp32 -> bf16 (vectorized) ----------------
__global__ void k_cast4(const float4* __restrict__ s, ushort4* __restrict__ d, int n4) {
  int i = blockIdx.x * blockDim.x + threadIdx.x;
  if (i < n4) {
    float4 v = s[i];
    ushort4 o;
    o.x = f2bf(v.x); o.y = f2bf(v.y); o.z = f2bf(v.z); o.w = f2bf(v.w);
    d[i] = o;
  }
}

// ---------------- CSR build ----------------
__global__ void k_hist(const int* __restrict__ dst, int E, int* __restrict__ deg) {
  int i = blockIdx.x * blockDim.x + threadIdx.x;
  if (i < E) atomicAdd(&deg[dst[i]], 1);
}

__global__ __launch_bounds__(1024) void k_scan1(const int* __restrict__ deg, int N,
                                                int* __restrict__ rowptr, int* __restrict__ bsum) {
  __shared__ int s[1024];
  int t = threadIdx.x;
  int i = blockIdx.x * 1024 + t;
  int val = (i < N) ? deg[i] : 0;
  s[t] = val;
  __syncthreads();
  for (int off = 1; off < 1024; off <<= 1) {
    int add = (t >= off) ? s[t - off] : 0;
    __syncthreads();
    s[t] += add;
    __syncthreads();
  }
  if (i < N) rowptr[i + 1] = s[t];
  if (t == 1023) bsum[blockIdx.x] = s[t];
}

__global__ void k_scan2(int* __restrict__ bsum, int nb) {
  if (threadIdx.x == 0 && blockIdx.x == 0) {
    int run = 0;
    for (int j = 0; j < nb; ++j) { int t = bsum[j]; bsum[j] = run; run += t; }
  }
}

__global__ void k_scan3(int* __restrict__ rowptr, const int* __restrict__ bsum, int N) {
  int i = blockIdx.x * blockDim.x + threadIdx.x;
  if (i < N) rowptr[i + 1] += bsum[i >> 10];
  if (i == 0) rowptr[0] = 0;
}

__global__ void k_scatter(const int* __restrict__ src, const int* __restrict__ dst, int E,
                          const int* __restrict__ rowptr, int* __restrict__ cur,
                          int* __restrict__ csr_src) {
  int i = blockIdx.x * blockDim.x + threadIdx.x;
  if (i < E) {
    int d = dst[i];
    int pos = rowptr[d] + atomicAdd(&cur[d], 1);
    csr_src[pos] = src[i];
  }
}

// ---------------- 64x64-per-wave GEMM tile (bf16 MFMA 16x16x32) ----------------
// (kept for k_qkv / k_proj; direct-global-load variant)
__device__ __forceinline__ void wave_tile64(const ushort* __restrict__ A, int lda, int row0, int nrows,
                                            const ushort* __restrict__ B, int ldb, int col0,
                                            int K, f32x4* acc) {
  int lane = threadIdx.x & 63;
  int m = lane & 15, quad = lane >> 4;
  const ushort* ap[4];
  const ushort* bp[4];
#pragma unroll
  for (int ri = 0; ri < 4; ++ri) {
    int r = row0 + ri * 16 + m;
    r = (r < nrows) ? r : (nrows - 1);
    ap[ri] = A + (size_t)r * lda + quad * 8;
  }
#pragma unroll
  for (int cj = 0; cj < 4; ++cj)
    bp[cj] = B + (size_t)(col0 + cj * 16 + m) * ldb + quad * 8;
  for (int k0 = 0; k0 < K; k0 += 32) {
    bf8 a[4], b[4];
#pragma unroll
    for (int ri = 0; ri < 4; ++ri) a[ri] = *(const bf8*)(ap[ri] + k0);
#pragma unroll
    for (int cj = 0; cj < 4; ++cj) b[cj] = *(const bf8*)(bp[cj] + k0);
#pragma unroll
    for (int ri = 0; ri < 4; ++ri)
#pragma unroll
      for (int cj = 0; cj < 4; ++cj)
        acc[ri * 4 + cj] = __builtin_amdgcn_mfma_f32_16x16x32_bf16(a[ri], b[cj], acc[ri * 4 + cj], 0, 0, 0);
  }
}

// ---------------- m97-style staged 128x128 GEMM core ----------------
// Stage one 128x32 bf16 tile (8 KB) into LDS via global_load_lds(16B).
// Swizzle: LDS granule (row, slot) holds src granule (row, slot^(row&3)) —
// involution applied on the SOURCE address here and on the READ below (G21).
// Wave w stages rows [w*32, w*32+32). Rows clamped to nr-1.
__device__ __forceinline__ void stage_tile(const ushort* __restrict__ S, int ld,
                                           int r0, int nr, int k0,
                                           ushort* lds, int wave, int lane) {
#pragma unroll
  for (int j = 0; j < 2; ++j) {
    int g = wave * 128 + j * 64 + lane;   // granule 0..511
    int row = g >> 2, slot = g & 3;
    int rr = r0 + row; rr = (rr < nr) ? rr : (nr - 1);
    const ushort* src = S + (size_t)rr * ld + k0 + ((slot ^ (row & 3)) << 3);
    gload_lds16(src, &lds[(size_t)(wave * 128 + j * 64) * 8]);
  }
}

// K-loop: 2 barriers per BK=32 step (m97 pattern); acc = 16 f32x4 per wave.
// Wave (w&1) -> row half, (w>>1) -> col quarter: rows r0w=(w&1)*64, cols c0w=(w>>1)*64.
__device__ __forceinline__ void gemm128_core(const ushort* __restrict__ A, int lda, int rowt, int nA,
                                             const ushort* __restrict__ B, int ldb, int colt, int nB,
                                             int K, ushort* lA, ushort* lB, f32x4* acc) {
  int tid = threadIdx.x;
  int wave = tid >> 6, lane = tid & 63;
  int m = lane & 15, quad = lane >> 4;
  int r0w = (wave & 1) * 64, c0w = (wave >> 1) * 64;
  int sw = (quad ^ (m & 3)) << 3;  // swizzled 16B slot (in ushorts)

  for (int k0 = 0; k0 < K; k0 += 32) {
    __syncthreads();  // prior step's LDS reads complete before overwrite
    stage_tile(A, lda, rowt, nA, k0, lA, wave, lane);
    stage_tile(B, ldb, colt, nB, k0, lB, wave, lane);
    __syncthreads();  // vmcnt(0) drained before barrier -> tiles ready

    bf8 a[4], b[4];
#pragma unroll
    for (int ri = 0; ri < 4; ++ri)
      a[ri] = *(const bf8*)&lA[(r0w + ri * 16 + m) * 32 + sw];
#pragma unroll
    for (int cj = 0; cj < 4; ++cj)
      b[cj] = *(const bf8*)&lB[(c0w + cj * 16 + m) * 32 + sw];
#pragma unroll
    for (int ri = 0; ri < 4; ++ri)
#pragma unroll
      for (int cj = 0; cj < 4; ++cj)
        acc[ri * 4 + cj] = __builtin_amdgcn_mfma_f32_16x16x32_bf16(a[ri], b[cj], acc[ri * 4 + cj], 0, 0, 0);
  }
}

// hidden-chunk GEMM: hid[.,0..512) = gelu(h @ W1c^T + b1c). Grid (391, 4).
__global__ __launch_bounds__(256) void k_g1(const ushort* __restrict__ h,
                                            const ushort* __restrict__ W1c,
                                            const float* __restrict__ b1c,
                                            ushort* __restrict__ hid, int N) {
  __shared__ ushort lA[128 * 32];
  __shared__ ushort lB[128 * 32];
  int rowt = blockIdx.x * 128, colt = blockIdx.y * 128;
  int tid = threadIdx.x;
  int wave = tid >> 6, lane = tid & 63, m = lane & 15, quad = lane >> 4;
  int r0w = (wave & 1) * 64, c0w = (wave >> 1) * 64;

  f32x4 acc[16];
#pragma unroll
  for (int j = 0; j < 16; ++j) acc[j] = (f32x4){0.f, 0.f, 0.f, 0.f};

  gemm128_core(h, CDIM, rowt, N, W1c, CDIM, colt, 512, CDIM, lA, lB, acc);

#pragma unroll
  for (int cj = 0; cj < 4; ++cj) {
    int col = colt + c0w + cj * 16 + m;  // hidden-local col, < 512
    float bs = b1c[col];
#pragma unroll
    for (int ri = 0; ri < 4; ++ri)
#pragma unroll
      for (int i = 0; i < 4; ++i) {
        int r = rowt + r0w + ri * 16 + quad * 4 + i;
        if (r < N) hid[(size_t)r * 512 + col] = f2bf(fast_gelu(acc[ri * 4 + cj][i] + bs));
      }
  }
}

// out-chunk GEMM: out += hid @ W2c^T (+ b2 on first pass). Grid (391, 2).
__global__ __launch_bounds__(256) void k_g2(const ushort* __restrict__ hid,
                                            const ushort* __restrict__ W2c,
                                            const float* __restrict__ b2,
                                            float* __restrict__ out, int N, int first) {
  __shared__ ushort lA[128 * 32];
  __shared__ ushort lB[128 * 32];
  int rowt = blockIdx.x * 128, colt = blockIdx.y * 128;
  int tid = threadIdx.x;
  int wave = tid >> 6, lane = tid & 63, m = lane & 15, quad = lane >> 4;
  int r0w = (wave & 1) * 64, c0w = (wave >> 1) * 64;

  f32x4 acc[16];
#pragma unroll
  for (int j = 0; j < 16; ++j) acc[j] = (f32x4){0.f, 0.f, 0.f, 0.f};

  gemm128_core(hid, 512, rowt, N, W2c, 1024, colt, 256, 512, lA, lB, acc);

#pragma unroll
  for (int cj = 0; cj < 4; ++cj) {
    int col = colt + c0w + cj * 16 + m;  // < 256
    float bs = first ? b2[col] : 0.f;
#pragma unroll
    for (int ri = 0; ri < 4; ++ri)
#pragma unroll
      for (int i = 0; i < 4; ++i) {
        int r = rowt + r0w + ri * 16 + quad * 4 + i;
        if (r < N) {
          size_t idx = (size_t)r * CDIM + col;
          out[idx] = out[idx] + acc[ri * 4 + cj][i] + bs;
        }
      }
  }
}

// q,k,v = feat @ W{q,k,v}^T + b ; block = 64 rows x 256 cols of one of q/k/v
__global__ __launch_bounds__(256) void k_qkv(const ushort* __restrict__ featb,
                                             const ushort* __restrict__ Wq, const ushort* __restrict__ Wk,
                                             const ushort* __restrict__ Wv,
                                             const float* __restrict__ bq, const float* __restrict__ bk,
                                             const float* __restrict__ bv,
                                             ushort* __restrict__ q, ushort* __restrict__ k,
                                             ushort* __restrict__ v, int N) {
  int rt = blockIdx.x, which = blockIdx.y;
  const ushort* W = (which == 0) ? Wq : (which == 1) ? Wk : Wv;
  const float* bias = (which == 0) ? bq : (which == 1) ? bk : bv;
  ushort* outp = (which == 0) ? q : (which == 1) ? k : v;
  int wave = threadIdx.x >> 6, lane = threadIdx.x & 63, m = lane & 15, quad = lane >> 4;
  int row0 = rt * 64, col0 = wave * 64;

  f32x4 acc[16];
#pragma unroll
  for (int j = 0; j < 16; ++j) acc[j] = (f32x4){0.f, 0.f, 0.f, 0.f};
  wave_tile64(featb, CDIM, row0, N, W, CDIM, col0, CDIM, acc);

#pragma unroll
  for (int cj = 0; cj < 4; ++cj) {
    int cc = col0 + cj * 16 + m;
    float bs = bias[cc];
#pragma unroll
    for (int ri = 0; ri < 4; ++ri)
#pragma unroll
      for (int i = 0; i < 4; ++i) {
        int r = row0 + ri * 16 + quad * 4 + i;
        if (r < N) outp[(size_t)r * CDIM + cc] = f2bf(acc[ri * 4 + cj][i] + bs);
      }
  }
}

// fused segment softmax + aggregate: one block (256 thr) per dst node, two-phase.
__global__ __launch_bounds__(256) void k_edge_agg(const ushort* __restrict__ q,
                                                  const ushort* __restrict__ kk,
                                                  const ushort* __restrict__ vv,
                                                  const int* __restrict__ rowptr,
                                                  const int* __restrict__ csr_src,
                                                  int N,
                                                  ushort* __restrict__ wv) {
  __shared__ float e_T[8 * 36];
  __shared__ int srcs[32];
  __shared__ float wdens[32];

  int n = blockIdx.x;
  int t = threadIdx.x;
  int lane = t & 63, wave = t >> 6;
  int el = t >> 3, h = t & 7;
  int h2 = t >> 5;

  int beg = rowptr[n], end = rowptr[n + 1];
  int deg = end - beg;

  float qf[32];
  {
    const ushort* qp = q + (size_t)n * CDIM + h * HDIM;
#pragma unroll
    for (int g = 0; g < 4; ++g) {
      bf8 qv = *(const bf8*)(qp + g * 8);
#pragma unroll
      for (int j = 0; j < 8; ++j) qf[g * 8 + j] = bf2f((ushort)qv[j]);
    }
  }

  float accv = 0.f;
  float den_part = 0.f;

  int nch = (deg + 31) >> 5;
  for (int ch = 0; ch < nch; ++ch) {
    int eidx = beg + ch * 32 + el;
    int src = 0;
    float e = 0.f;
    if (eidx < end) {
      src = csr_src[eidx];
      const ushort* kp = kk + (size_t)src * CDIM + h * HDIM;
      float dot = 0.f;
#pragma unroll
      for (int g = 0; g < 4; ++g) {
        bf8 kv = *(const bf8*)(kp + g * 8);
#pragma unroll
        for (int j = 0; j < 8; ++j) dot = fmaf(qf[g * 8 + j], bf2f((ushort)kv[j]), dot);
      }
      float s = dot * 0.17677669529663687f;
      s = fminf(10.f, fmaxf(-10.f, s));
      e = __expf(s - 10.f);
    }
    e_T[h * 36 + el] = e;
    if (h == 0) srcs[el] = src;
    den_part += e;
    __syncthreads();

#pragma unroll
    for (int g4 = 0; g4 < 8; ++g4) {
      int4 s4 = *(const int4*)&srcs[g4 * 4];
      float4 e4 = *(const float4*)&e_T[h2 * 36 + g4 * 4];
      accv = fmaf(e4.x, bf2f(vv[(size_t)s4.x * CDIM + t]), accv);
      accv = fmaf(e4.y, bf2f(vv[(size_t)s4.y * CDIM + t]), accv);
      accv = fmaf(e4.z, bf2f(vv[(size_t)s4.z * CDIM + t]), accv);
      accv = fmaf(e4.w, bf2f(vv[(size_t)s4.w * CDIM + t]), accv);
    }
    __syncthreads();
  }

  float d = den_part;
  d += __shfl_xor(d, 8);
  d += __shfl_xor(d, 16);
  d += __shfl_xor(d, 32);
  if (lane < 8) wdens[wave * 8 + lane] = d;
  __syncthreads();
  float den = wdens[h2] + wdens[8 + h2] + wdens[16 + h2] + wdens[24 + h2];
  wv[(size_t)n * CDIM + t] = f2bf((deg > 0) ? accv / den : 0.f);
}

// x = feat + wv @ Wp^T + bp  (fp32 out); block = 64 rows x 256 cols
__global__ __launch_bounds__(256) void k_proj(const ushort* __restrict__ wv,
                                              const ushort* __restrict__ Wp,
                                              const float* __restrict__ bp,
                                              const float* __restrict__ feat,
                                              float* __restrict__ x, int N) {
  int rt = blockIdx.x;
  int wave = threadIdx.x >> 6, lane = threadIdx.x & 63, m = lane & 15, quad = lane >> 4;
  int row0 = rt * 64, col0 = wave * 64;
  f32x4 acc[16];
#pragma unroll
  for (int j = 0; j < 16; ++j) acc[j] = (f32x4){0.f, 0.f, 0.f, 0.f};
  wave_tile64(wv, CDIM, row0, N, Wp, CDIM, col0, CDIM, acc);
#pragma unroll
  for (int cj = 0; cj < 4; ++cj) {
    int cc = col0 + cj * 16 + m;
    float bs = bp[cc];
#pragma unroll
    for (int ri = 0; ri < 4; ++ri)
#pragma unroll
      for (int i = 0; i < 4; ++i) {
        int r = row0 + ri * 16 + quad * 4 + i;
        if (r < N) x[(size_t)r * CDIM + cc] = acc[ri * 4 + cj][i] + bs + feat[(size_t)r * CDIM + cc];
      }
  }
}

// h = layernorm(x)*g + b -> bf16 ; ALSO copies x into out (residual base),
// freeing the x region for the hidden-chunk buffer.
__global__ __launch_bounds__(256) void k_ln(const float* __restrict__ x,
                                            const float* __restrict__ g,
                                            const float* __restrict__ b,
                                            ushort* __restrict__ h,
                                            float* __restrict__ out) {
  int row = blockIdx.x * 4 + (threadIdx.x >> 6);
  int lane = threadIdx.x & 63;
  const float* xr = x + (size_t)row * CDIM;
  float4 xv = *(const float4*)(xr + lane * 4);
  *(float4*)(out + (size_t)row * CDIM + lane * 4) = xv;  // out = x
  float s = xv.x + xv.y + xv.z + xv.w;
  float ss = xv.x * xv.x + xv.y * xv.y + xv.z * xv.z + xv.w * xv.w;
#pragma unroll
  for (int msk = 1; msk <= 32; msk <<= 1) {
    s += __shfl_xor(s, msk);
    ss += __shfl_xor(ss, msk);
  }
  float mu = s * (1.f / CDIM);
  float var = ss * (1.f / CDIM) - mu * mu;
  float rs = rsqrtf(var + 1e-5f);
  float xe[4] = {xv.x, xv.y, xv.z, xv.w};
#pragma unroll
  for (int t = 0; t < 4; ++t) {
    int cc = lane * 4 + t;
    h[(size_t)row * CDIM + cc] = f2bf((xe[t] - mu) * rs * g[cc] + b[cc]);
  }
}

extern "C" void kernel_launch(void* const* d_in, const int* in_sizes, int n_in,
                              void* d_out, int out_size, void* d_ws, size_t ws_size,
                              hipStream_t stream) {
  const float* feat = (const float*)d_in[0];
  const int* esrc = (const int*)d_in[1];
  const int* edst = (const int*)d_in[2];
  const float* Wq = (const float*)d_in[3];
  const float* bq = (const float*)d_in[4];
  const float* Wk = (const float*)d_in[5];
  const float* bk = (const float*)d_in[6];
  const float* Wv = (const float*)d_in[7];
  const float* bv = (const float*)d_in[8];
  const float* Wp = (const float*)d_in[9];
  const float* bp = (const float*)d_in[10];
  const float* lng = (const float*)d_in[11];
  const float* lnb = (const float*)d_in[12];
  const float* W1 = (const float*)d_in[13];
  const float* b1 = (const float*)d_in[14];
  const float* W2 = (const float*)d_in[15];
  const float* b2 = (const float*)d_in[16];

  const int N = in_sizes[0] / CDIM;  // 50000
  const int E = in_sizes[1];         // 1600000
  const size_t NC2 = (size_t)N * CDIM * 2;  // bf16 plane: 25.6 MB

  // Workspace layout (lifetime overlays):
  //   [0,NC2) q | x(f32, 2*NC2) overlays q+k from proj on | hid (bf16 50000x512,
  //       exactly 2*NC2) overlays x after k_ln copies x->out
  //   [NC2,2NC2) k
  //   [2NC2,3NC2) v | h(bf16) overlays v from ln on
  //   [3NC2,4NC2) wv | featb(bf16) overlays (disjoint lifetime)
  //   [4NC2,..) CSR, then bf16 weights
  char* w = (char*)d_ws;
  ushort* q   = (ushort*)(w);
  ushort* kk  = (ushort*)(w + NC2);
  ushort* vv  = (ushort*)(w + 2 * NC2);
  ushort* wvb = (ushort*)(w + 3 * NC2);
  ushort* featb = (ushort*)(w + 3 * NC2);
  float*  x   = (float*)(w);               // overlays q+k
  ushort* h   = (ushort*)(w + 2 * NC2);    // overlays v
  ushort* hid = (ushort*)(w);              // overlays x (dead after k_ln)

  char* csr = w + 4 * NC2;
  int* rowptr  = (int*)(csr);
  int* deg     = (int*)(csr + 200064);
  int* csr_src = (int*)(csr + 400128);
  int* bsum    = (int*)(csr + 400128 + (size_t)E * 4);

  char* wb = csr + 400128 + (size_t)E * 4 + 256;
  ushort* Wqb = (ushort*)(wb);
  ushort* Wkb = (ushort*)(wb + 131072);
  ushort* Wvb = (ushort*)(wb + 262144);
  ushort* Wpb = (ushort*)(wb + 393216);
  ushort* W1b = (ushort*)(wb + 524288);
  ushort* W2b = (ushort*)(wb + 1048576);

  const int nb = (N + 1023) / 1024;
  const int RT64 = (N + 63) / 64;    // 782
  const int RT128 = (N + 127) / 128; // 391

  // weight + feat casts
  k_cast4<<<(16384 + 255) / 256, 256, 0, stream>>>((const float4*)Wq, (ushort4*)Wqb, 16384);
  k_cast4<<<(16384 + 255) / 256, 256, 0, stream>>>((const float4*)Wk, (ushort4*)Wkb, 16384);
  k_cast4<<<(16384 + 255) / 256, 256, 0, stream>>>((const float4*)Wv, (ushort4*)Wvb, 16384);
  k_cast4<<<(16384 + 255) / 256, 256, 0, stream>>>((const float4*)Wp, (ushort4*)Wpb, 16384);
  k_cast4<<<(65536 + 255) / 256, 256, 0, stream>>>((const float4*)W1, (ushort4*)W1b, 65536);
  k_cast4<<<(65536 + 255) / 256, 256, 0, stream>>>((const float4*)W2, (ushort4*)W2b, 65536);
  {
    int n4 = N * CDIM / 4;
    k_cast4<<<(n4 + 255) / 256, 256, 0, stream>>>((const float4*)feat, (ushort4*)featb, n4);
  }

  // CSR build (group edges by dst)
  hipMemsetAsync(deg, 0, (size_t)N * 4, stream);
  k_hist<<<(E + 255) / 256, 256, 0, stream>>>(edst, E, deg);
  k_scan1<<<nb, 1024, 0, stream>>>(deg, N, rowptr, bsum);
  k_scan2<<<1, 64, 0, stream>>>(bsum, nb);
  k_scan3<<<(N + 255) / 256, 256, 0, stream>>>(rowptr, bsum, N);
  hipMemsetAsync(deg, 0, (size_t)N * 4, stream);
  k_scatter<<<(E + 255) / 256, 256, 0, stream>>>(esrc, edst, E, rowptr, deg, csr_src);

  // QKV projections
  k_qkv<<<dim3(RT64, 3), 256, 0, stream>>>(featb, Wqb, Wkb, Wvb, bq, bk, bv, q, kk, vv, N);
  // fused segment-softmax + aggregate
  k_edge_agg<<<N, 256, 0, stream>>>(q, kk, vv, rowptr, csr_src, N, wvb);
  // x = feat + wv@Wp^T + bp
  k_proj<<<RT64, 256, 0, stream>>>(wvb, Wpb, bp, feat, x, N);
  // h = LN(x); out = x (residual base; x region then free for hid)
  k_ln<<<N / 4, 256, 0, stream>>>(x, lng, lnb, h, (float*)d_out);

  // MLP: hidden in 2 passes of 512 cols; staged 128x128 GEMMs.
  for (int c = 0; c < 2; ++c) {
    // hid = gelu(h @ W1[c*512.., :]^T + b1[c*512..])
    k_g1<<<dim3(RT128, 4), 256, 0, stream>>>(h, W1b + (size_t)c * 512 * CDIM,
                                             b1 + c * 512, hid, N);
    // out += hid @ W2[:, c*512..]^T (+ b2 on first pass)
    k_g2<<<dim3(RT128, 2), 256, 0, stream>>>(hid, W2b + (size_t)c * 512,
                                             b2, (float*)d_out, N, c == 0 ? 1 : 0);
  }
}

// Round 6
// 871.170 us; speedup vs baseline: 1.1700x; 1.0946x over previous
//
#include <hip/hip_runtime.h>
#include <hip/hip_bf16.h>

#define CDIM 256
#define NH 8
#define HDIM 32

typedef short bf8 __attribute__((ext_vector_type(8)));
typedef float f32x4 __attribute__((ext_vector_type(4)));

__device__ __forceinline__ float bf2f(ushort u) {
  union { unsigned int i; float f; } x; x.i = ((unsigned int)u) << 16; return x.f;
}
__device__ __forceinline__ ushort f2bf(float f) {
  union { float f; unsigned int i; } x; x.f = f;
  unsigned int lsb = (x.i >> 16) & 1u;
  unsigned int r = x.i + 0x7fffu + lsb;
  return (ushort)(r >> 16);
}

// fast gelu (tanh form): max err ~2e-4 where pre-acts live (sigma~0.32).
__device__ __forceinline__ float fast_gelu(float t) {
  float u = 0.7978845608028654f * (t + 0.044715f * t * t * t);
  float ez = __expf(2.f * u);
  float th = 1.f - 2.f * __builtin_amdgcn_rcpf(ez + 1.f);
  return 0.5f * t * (1.f + th);
}

// async global->LDS, 16B per lane; LDS dest = wave-uniform base + lane*16.
__device__ __forceinline__ void gload_lds16(const ushort* g, ushort* l) {
  __builtin_amdgcn_global_load_lds((const __attribute__((address_space(1))) unsigned int*)g,
                                   (__attribute__((address_space(3))) unsigned int*)l,
                                   16, 0, 0);
}

// ---------------- casts fp32 -> bf16 (vectorized) ----------------
__global__ void k_cast4(const float4* __restrict__ s, ushort4* __restrict__ d, int n4) {
  int i = blockIdx.x * blockDim.x + threadIdx.x;
  if (i < n4) {
    float4 v = s[i];
    ushort4 o;
    o.x = f2bf(v.x); o.y = f2bf(v.y); o.z = f2bf(v.z); o.w = f2bf(v.w);
    d[i] = o;
  }
}

// ---------------- CSR build ----------------
__global__ void k_hist(const int* __restrict__ dst, int E, int* __restrict__ deg) {
  int i = blockIdx.x * blockDim.x + threadIdx.x;
  if (i < E) atomicAdd(&deg[dst[i]], 1);
}

__global__ __launch_bounds__(1024) void k_scan1(const int* __restrict__ deg, int N,
                                                int* __restrict__ rowptr, int* __restrict__ bsum) {
  __shared__ int s[1024];
  int t = threadIdx.x;
  int i = blockIdx.x * 1024 + t;
  int val = (i < N) ? deg[i] : 0;
  s[t] = val;
  __syncthreads();
  for (int off = 1; off < 1024; off <<= 1) {
    int add = (t >= off) ? s[t - off] : 0;
    __syncthreads();
    s[t] += add;
    __syncthreads();
  }
  if (i < N) rowptr[i + 1] = s[t];
  if (t == 1023) bsum[blockIdx.x] = s[t];
}

__global__ void k_scan2(int* __restrict__ bsum, int nb) {
  if (threadIdx.x == 0 && blockIdx.x == 0) {
    int run = 0;
    for (int j = 0; j < nb; ++j) { int t = bsum[j]; bsum[j] = run; run += t; }
  }
}

__global__ void k_scan3(int* __restrict__ rowptr, const int* __restrict__ bsum, int N) {
  int i = blockIdx.x * blockDim.x + threadIdx.x;
  if (i < N) rowptr[i + 1] += bsum[i >> 10];
  if (i == 0) rowptr[0] = 0;
}

__global__ void k_scatter(const int* __restrict__ src, const int* __restrict__ dst, int E,
                          const int* __restrict__ rowptr, int* __restrict__ cur,
                          int* __restrict__ csr_src) {
  int i = blockIdx.x * blockDim.x + threadIdx.x;
  if (i < E) {
    int d = dst[i];
    int pos = rowptr[d] + atomicAdd(&cur[d], 1);
    csr_src[pos] = src[i];
  }
}

// ---------------- m97-style staged 128x128 GEMM core ----------------
// Stage one 128x32 bf16 tile (8 KB) into LDS via global_load_lds(16B).
// Swizzle: LDS granule (row, slot) holds src granule (row, slot^(row&3)) —
// involution on SOURCE address here and on the READ below (G21).
__device__ __forceinline__ void stage_tile(const ushort* __restrict__ S, int ld,
                                           int r0, int nr, int k0,
                                           ushort* lds, int wave, int lane) {
#pragma unroll
  for (int j = 0; j < 2; ++j) {
    int g = wave * 128 + j * 64 + lane;   // granule 0..511
    int row = g >> 2, slot = g & 3;
    int rr = r0 + row; rr = (rr < nr) ? rr : (nr - 1);
    const ushort* src = S + (size_t)rr * ld + k0 + ((slot ^ (row & 3)) << 3);
    gload_lds16(src, &lds[(size_t)(wave * 128 + j * 64) * 8]);
  }
}

// K-loop: 2 barriers per BK=32 step (m97 pattern); acc = 16 f32x4 per wave.
__device__ __forceinline__ void gemm128_core(const ushort* __restrict__ A, int lda, int rowt, int nA,
                                             const ushort* __restrict__ B, int ldb, int colt, int nB,
                                             int K, ushort* lA, ushort* lB, f32x4* acc) {
  int tid = threadIdx.x;
  int wave = tid >> 6, lane = tid & 63;
  int m = lane & 15, quad = lane >> 4;
  int r0w = (wave & 1) * 64, c0w = (wave >> 1) * 64;
  int sw = (quad ^ (m & 3)) << 3;  // swizzled 16B slot (in ushorts)

  for (int k0 = 0; k0 < K; k0 += 32) {
    __syncthreads();  // prior step's LDS reads complete before overwrite
    stage_tile(A, lda, rowt, nA, k0, lA, wave, lane);
    stage_tile(B, ldb, colt, nB, k0, lB, wave, lane);
    __syncthreads();  // vmcnt(0) drained before barrier -> tiles ready

    bf8 a[4], b[4];
#pragma unroll
    for (int ri = 0; ri < 4; ++ri)
      a[ri] = *(const bf8*)&lA[(r0w + ri * 16 + m) * 32 + sw];
#pragma unroll
    for (int cj = 0; cj < 4; ++cj)
      b[cj] = *(const bf8*)&lB[(c0w + cj * 16 + m) * 32 + sw];
#pragma unroll
    for (int ri = 0; ri < 4; ++ri)
#pragma unroll
      for (int cj = 0; cj < 4; ++cj)
        acc[ri * 4 + cj] = __builtin_amdgcn_mfma_f32_16x16x32_bf16(a[ri], b[cj], acc[ri * 4 + cj], 0, 0, 0);
  }
}

// fused QKV: [q|k|v](cols 0..767) = feat @ [Wq;Wk;Wv]^T + b. Grid (391, 6).
// Wqkv rows 0-255 = Wq, 256-511 = Wk, 512-767 = Wv (contiguous casts).
__global__ __launch_bounds__(256) void k_qkvf(const ushort* __restrict__ featb,
                                              const ushort* __restrict__ Wqkv,
                                              const float* __restrict__ bq, const float* __restrict__ bk,
                                              const float* __restrict__ bv,
                                              ushort* __restrict__ q, ushort* __restrict__ k,
                                              ushort* __restrict__ v, int N) {
  __shared__ ushort lA[128 * 32];
  __shared__ ushort lB[128 * 32];
  int rowt = blockIdx.x * 128, colt = blockIdx.y * 128;
  int which = colt >> 8;  // 0=q,1=k,2=v (128-tile never straddles a 256 group)
  const float* bias = (which == 0) ? bq : (which == 1) ? bk : bv;
  ushort* outp = (which == 0) ? q : (which == 1) ? k : v;
  int tid = threadIdx.x;
  int wave = tid >> 6, lane = tid & 63, m = lane & 15, quad = lane >> 4;
  int r0w = (wave & 1) * 64, c0w = (wave >> 1) * 64;

  f32x4 acc[16];
#pragma unroll
  for (int j = 0; j < 16; ++j) acc[j] = (f32x4){0.f, 0.f, 0.f, 0.f};

  gemm128_core(featb, CDIM, rowt, N, Wqkv, CDIM, colt, 768, CDIM, lA, lB, acc);

#pragma unroll
  for (int cj = 0; cj < 4; ++cj) {
    int col = (colt + c0w + cj * 16 + m) & 255;
    float bs = bias[col];
#pragma unroll
    for (int ri = 0; ri < 4; ++ri)
#pragma unroll
      for (int i = 0; i < 4; ++i) {
        int r = rowt + r0w + ri * 16 + quad * 4 + i;
        if (r < N) outp[(size_t)r * CDIM + col] = f2bf(acc[ri * 4 + cj][i] + bs);
      }
  }
}

// x = feat + wv @ Wp^T + bp  (fp32 out); staged core. Grid (391, 2).
__global__ __launch_bounds__(256) void k_proj(const ushort* __restrict__ wv,
                                              const ushort* __restrict__ Wp,
                                              const float* __restrict__ bp,
                                              const float* __restrict__ feat,
                                              float* __restrict__ x, int N) {
  __shared__ ushort lA[128 * 32];
  __shared__ ushort lB[128 * 32];
  int rowt = blockIdx.x * 128, colt = blockIdx.y * 128;
  int tid = threadIdx.x;
  int wave = tid >> 6, lane = tid & 63, m = lane & 15, quad = lane >> 4;
  int r0w = (wave & 1) * 64, c0w = (wave >> 1) * 64;

  f32x4 acc[16];
#pragma unroll
  for (int j = 0; j < 16; ++j) acc[j] = (f32x4){0.f, 0.f, 0.f, 0.f};

  gemm128_core(wv, CDIM, rowt, N, Wp, CDIM, colt, 256, CDIM, lA, lB, acc);

#pragma unroll
  for (int cj = 0; cj < 4; ++cj) {
    int col = colt + c0w + cj * 16 + m;
    float bs = bp[col];
#pragma unroll
    for (int ri = 0; ri < 4; ++ri)
#pragma unroll
      for (int i = 0; i < 4; ++i) {
        int r = rowt + r0w + ri * 16 + quad * 4 + i;
        if (r < N)
          x[(size_t)r * CDIM + col] = acc[ri * 4 + cj][i] + bs + feat[(size_t)r * CDIM + col];
      }
  }
}

// hidden-chunk GEMM: hid[.,0..512) = gelu(h @ W1c^T + b1c). Grid (391, 4).
__global__ __launch_bounds__(256) void k_g1(const ushort* __restrict__ h,
                                            const ushort* __restrict__ W1c,
                                            const float* __restrict__ b1c,
                                            ushort* __restrict__ hid, int N) {
  __shared__ ushort lA[128 * 32];
  __shared__ ushort lB[128 * 32];
  int rowt = blockIdx.x * 128, colt = blockIdx.y * 128;
  int tid = threadIdx.x;
  int wave = tid >> 6, lane = tid & 63, m = lane & 15, quad = lane >> 4;
  int r0w = (wave & 1) * 64, c0w = (wave >> 1) * 64;

  f32x4 acc[16];
#pragma unroll
  for (int j = 0; j < 16; ++j) acc[j] = (f32x4){0.f, 0.f, 0.f, 0.f};

  gemm128_core(h, CDIM, rowt, N, W1c, CDIM, colt, 512, CDIM, lA, lB, acc);

#pragma unroll
  for (int cj = 0; cj < 4; ++cj) {
    int col = colt + c0w + cj * 16 + m;  // hidden-local col, < 512
    float bs = b1c[col];
#pragma unroll
    for (int ri = 0; ri < 4; ++ri)
#pragma unroll
      for (int i = 0; i < 4; ++i) {
        int r = rowt + r0w + ri * 16 + quad * 4 + i;
        if (r < N) hid[(size_t)r * 512 + col] = f2bf(fast_gelu(acc[ri * 4 + cj][i] + bs));
      }
  }
}

// out-chunk GEMM: out += hid @ W2c^T (+ b2 on first pass). Grid (391, 2).
__global__ __launch_bounds__(256) void k_g2(const ushort* __restrict__ hid,
                                            const ushort* __restrict__ W2c,
                                            const float* __restrict__ b2,
                                            float* __restrict__ out, int N, int first) {
  __shared__ ushort lA[128 * 32];
  __shared__ ushort lB[128 * 32];
  int rowt = blockIdx.x * 128, colt = blockIdx.y * 128;
  int tid = threadIdx.x;
  int wave = tid >> 6, lane = tid & 63, m = lane & 15, quad = lane >> 4;
  int r0w = (wave & 1) * 64, c0w = (wave >> 1) * 64;

  f32x4 acc[16];
#pragma unroll
  for (int j = 0; j < 16; ++j) acc[j] = (f32x4){0.f, 0.f, 0.f, 0.f};

  gemm128_core(hid, 512, rowt, N, W2c, 1024, colt, 256, 512, lA, lB, acc);

#pragma unroll
  for (int cj = 0; cj < 4; ++cj) {
    int col = colt + c0w + cj * 16 + m;  // < 256
    float bs = first ? b2[col] : 0.f;
#pragma unroll
    for (int ri = 0; ri < 4; ++ri)
#pragma unroll
      for (int i = 0; i < 4; ++i) {
        int r = rowt + r0w + ri * 16 + quad * 4 + i;
        if (r < N) {
          size_t idx = (size_t)r * CDIM + col;
          out[idx] = out[idx] + acc[ri * 4 + cj][i] + bs;
        }
      }
  }
}

// fused segment softmax + aggregate, wave-per-dst, barrier-free.
// Wave lanes: dot phase (el=lane>>3 edge-slot, h=lane&7 head);
// agg phase: lane owns channels [lane*4, lane*4+4) (head = lane>>3).
// e/src redistributed via __shfl; invalid tail edges use e=0/src=0 (no guards).
__global__ __launch_bounds__(256) void k_edge_agg(const ushort* __restrict__ q,
                                                  const ushort* __restrict__ kk,
                                                  const ushort* __restrict__ vv,
                                                  const int* __restrict__ rowptr,
                                                  const int* __restrict__ csr_src,
                                                  int N,
                                                  ushort* __restrict__ wv) {
  int wave = threadIdx.x >> 6, lane = threadIdx.x & 63;
  int n = blockIdx.x * 4 + wave;
  if (n >= N) return;  // wave-uniform; no barriers in this kernel

  int el = lane >> 3, h = lane & 7;
  int beg = rowptr[n], end = rowptr[n + 1];
  int deg = end - beg;

  // q slice for head h into registers (f32)
  float qf[32];
  {
    const ushort* qp = q + (size_t)n * CDIM + h * HDIM;
#pragma unroll
    for (int g = 0; g < 4; ++g) {
      bf8 qv = *(const bf8*)(qp + g * 8);
#pragma unroll
      for (int j = 0; j < 8; ++j) qf[g * 8 + j] = bf2f((ushort)qv[j]);
    }
  }

  float accv[4] = {0.f, 0.f, 0.f, 0.f};
  float den_part = 0.f;

  for (int c0 = 0; c0 < deg; c0 += 8) {
    int src = 0;
    float e = 0.f;
    if (c0 + el < deg) {
      src = csr_src[beg + c0 + el];
      const ushort* kp = kk + (size_t)src * CDIM + h * HDIM;
      float dot = 0.f;
#pragma unroll
      for (int g = 0; g < 4; ++g) {
        bf8 kv = *(const bf8*)(kp + g * 8);
#pragma unroll
        for (int j = 0; j < 8; ++j) dot = fmaf(qf[g * 8 + j], bf2f((ushort)kv[j]), dot);
      }
      float s = dot * 0.17677669529663687f;  // 1/sqrt(32)
      s = fminf(10.f, fmaxf(-10.f, s));
      e = __expf(s - 10.f);  // fixed shift: scores clamped, softmax shift-invariant
    }
    den_part += e;

    // aggregate these 8 edges: lane reads its 4 channels of V[src_j], weight e_j[head]
#pragma unroll
    for (int j = 0; j < 8; ++j) {
      int sj = __shfl(src, j << 3);
      float ej = __shfl(e, (j << 3) | (lane >> 3));
      ushort4 v4 = *(const ushort4*)(vv + (size_t)sj * CDIM + lane * 4);
      accv[0] = fmaf(ej, bf2f(v4.x), accv[0]);
      accv[1] = fmaf(ej, bf2f(v4.y), accv[1]);
      accv[2] = fmaf(ej, bf2f(v4.z), accv[2]);
      accv[3] = fmaf(ej, bf2f(v4.w), accv[3]);
    }
  }

  // den[h] = sum over el lanes (xor over bits 3..5), then broadcast to channel lanes
  float den = den_part;
  den += __shfl_xor(den, 8);
  den += __shfl_xor(den, 16);
  den += __shfl_xor(den, 32);
  float denh = __shfl(den, lane >> 3);  // lane L needs den of head L>>3

  float inv = (deg > 0) ? (1.f / denh) : 0.f;
  ushort4 o;
  o.x = f2bf(accv[0] * inv);
  o.y = f2bf(accv[1] * inv);
  o.z = f2bf(accv[2] * inv);
  o.w = f2bf(accv[3] * inv);
  *(ushort4*)(wv + (size_t)n * CDIM + lane * 4) = o;
}

// h = layernorm(x)*g + b -> bf16 ; ALSO copies x into out (residual base),
// freeing the x region for the hidden-chunk buffer.
__global__ __launch_bounds__(256) void k_ln(const float* __restrict__ x,
                                            const float* __restrict__ g,
                                            const float* __restrict__ b,
                                            ushort* __restrict__ h,
                                            float* __restrict__ out) {
  int row = blockIdx.x * 4 + (threadIdx.x >> 6);
  int lane = threadIdx.x & 63;
  const float* xr = x + (size_t)row * CDIM;
  float4 xv = *(const float4*)(xr + lane * 4);
  *(float4*)(out + (size_t)row * CDIM + lane * 4) = xv;  // out = x
  float s = xv.x + xv.y + xv.z + xv.w;
  float ss = xv.x * xv.x + xv.y * xv.y + xv.z * xv.z + xv.w * xv.w;
#pragma unroll
  for (int msk = 1; msk <= 32; msk <<= 1) {
    s += __shfl_xor(s, msk);
    ss += __shfl_xor(ss, msk);
  }
  float mu = s * (1.f / CDIM);
  float var = ss * (1.f / CDIM) - mu * mu;
  float rs = rsqrtf(var + 1e-5f);
  float xe[4] = {xv.x, xv.y, xv.z, xv.w};
#pragma unroll
  for (int t = 0; t < 4; ++t) {
    int cc = lane * 4 + t;
    h[(size_t)row * CDIM + cc] = f2bf((xe[t] - mu) * rs * g[cc] + b[cc]);
  }
}

extern "C" void kernel_launch(void* const* d_in, const int* in_sizes, int n_in,
                              void* d_out, int out_size, void* d_ws, size_t ws_size,
                              hipStream_t stream) {
  const float* feat = (const float*)d_in[0];
  const int* esrc = (const int*)d_in[1];
  const int* edst = (const int*)d_in[2];
  const float* Wq = (const float*)d_in[3];
  const float* bq = (const float*)d_in[4];
  const float* Wk = (const float*)d_in[5];
  const float* bk = (const float*)d_in[6];
  const float* Wv = (const float*)d_in[7];
  const float* bv = (const float*)d_in[8];
  const float* Wp = (const float*)d_in[9];
  const float* bp = (const float*)d_in[10];
  const float* lng = (const float*)d_in[11];
  const float* lnb = (const float*)d_in[12];
  const float* W1 = (const float*)d_in[13];
  const float* b1 = (const float*)d_in[14];
  const float* W2 = (const float*)d_in[15];
  const float* b2 = (const float*)d_in[16];

  const int N = in_sizes[0] / CDIM;  // 50000
  const int E = in_sizes[1];         // 1600000
  const size_t NC2 = (size_t)N * CDIM * 2;  // bf16 plane: 25.6 MB

  // Workspace layout (lifetime overlays):
  //   [0,NC2) q | x(f32, 2*NC2) overlays q+k from proj on | hid (bf16 50000x512)
  //       overlays x after k_ln copies x->out
  //   [NC2,2NC2) k
  //   [2NC2,3NC2) v | h(bf16) overlays v from ln on
  //   [3NC2,4NC2) wv | featb(bf16) overlays (disjoint lifetime)
  //   [4NC2,..) CSR, then bf16 weights (Wq,Wk,Wv contiguous = fused Wqkv)
  char* w = (char*)d_ws;
  ushort* q   = (ushort*)(w);
  ushort* kk  = (ushort*)(w + NC2);
  ushort* vv  = (ushort*)(w + 2 * NC2);
  ushort* wvb = (ushort*)(w + 3 * NC2);
  ushort* featb = (ushort*)(w + 3 * NC2);
  float*  x   = (float*)(w);               // overlays q+k
  ushort* h   = (ushort*)(w + 2 * NC2);    // overlays v
  ushort* hid = (ushort*)(w);              // overlays x (dead after k_ln)

  char* csr = w + 4 * NC2;
  int* rowptr  = (int*)(csr);
  int* deg     = (int*)(csr + 200064);
  int* csr_src = (int*)(csr + 400128);
  int* bsum    = (int*)(csr + 400128 + (size_t)E * 4);

  char* wb = csr + 400128 + (size_t)E * 4 + 256;
  ushort* Wqb = (ushort*)(wb);
  ushort* Wkb = (ushort*)(wb + 131072);
  ushort* Wvb = (ushort*)(wb + 262144);
  ushort* Wpb = (ushort*)(wb + 393216);
  ushort* W1b = (ushort*)(wb + 524288);
  ushort* W2b = (ushort*)(wb + 1048576);

  const int nb = (N + 1023) / 1024;
  const int RT128 = (N + 127) / 128; // 391

  // weight + feat casts (Wq/Wk/Wv land contiguously -> fused Wqkv matrix)
  k_cast4<<<(16384 + 255) / 256, 256, 0, stream>>>((const float4*)Wq, (ushort4*)Wqb, 16384);
  k_cast4<<<(16384 + 255) / 256, 256, 0, stream>>>((const float4*)Wk, (ushort4*)Wkb, 16384);
  k_cast4<<<(16384 + 255) / 256, 256, 0, stream>>>((const float4*)Wv, (ushort4*)Wvb, 16384);
  k_cast4<<<(16384 + 255) / 256, 256, 0, stream>>>((const float4*)Wp, (ushort4*)Wpb, 16384);
  k_cast4<<<(65536 + 255) / 256, 256, 0, stream>>>((const float4*)W1, (ushort4*)W1b, 65536);
  k_cast4<<<(65536 + 255) / 256, 256, 0, stream>>>((const float4*)W2, (ushort4*)W2b, 65536);
  {
    int n4 = N * CDIM / 4;
    k_cast4<<<(n4 + 255) / 256, 256, 0, stream>>>((const float4*)feat, (ushort4*)featb, n4);
  }

  // CSR build (group edges by dst)
  hipMemsetAsync(deg, 0, (size_t)N * 4, stream);
  k_hist<<<(E + 255) / 256, 256, 0, stream>>>(edst, E, deg);
  k_scan1<<<nb, 1024, 0, stream>>>(deg, N, rowptr, bsum);
  k_scan2<<<1, 64, 0, stream>>>(bsum, nb);
  k_scan3<<<(N + 255) / 256, 256, 0, stream>>>(rowptr, bsum, N);
  hipMemsetAsync(deg, 0, (size_t)N * 4, stream);
  k_scatter<<<(E + 255) / 256, 256, 0, stream>>>(esrc, edst, E, rowptr, deg, csr_src);

  // fused QKV projection (one staged GEMM, feat read once)
  k_qkvf<<<dim3(RT128, 6), 256, 0, stream>>>(featb, Wqb, bq, bk, bv, q, kk, vv, N);
  // fused segment-softmax + aggregate (wave-per-dst, barrier-free)
  k_edge_agg<<<(N + 3) / 4, 256, 0, stream>>>(q, kk, vv, rowptr, csr_src, N, wvb);
  // x = feat + wv@Wp^T + bp (staged core)
  k_proj<<<dim3(RT128, 2), 256, 0, stream>>>(wvb, Wpb, bp, feat, x, N);
  // h = LN(x); out = x (residual base; x region then free for hid)
  k_ln<<<N / 4, 256, 0, stream>>>(x, lng, lnb, h, (float*)d_out);

  // MLP: hidden in 2 passes of 512 cols; staged 128x128 GEMMs.
  for (int c = 0; c < 2; ++c) {
    k_g1<<<dim3(RT128, 4), 256, 0, stream>>>(h, W1b + (size_t)c * 512 * CDIM,
                                             b1 + c * 512, hid, N);
    k_g2<<<dim3(RT128, 2), 256, 0, stream>>>(hid, W2b + (size_t)c * 512,
                                             b2, (float*)d_out, N, c == 0 ? 1 : 0);
  }
}

// Round 8
// 780.596 us; speedup vs baseline: 1.3058x; 1.1160x over previous
//
#include <hip/hip_runtime.h>
#include <hip/hip_bf16.h>

#define CDIM 256
#define NH 8
#define HDIM 32

typedef short bf8 __attribute__((ext_vector_type(8)));
typedef float f32x4 __attribute__((ext_vector_type(4)));
typedef float f32x2 __attribute__((ext_vector_type(2)));

__device__ __forceinline__ float bf2f(ushort u) {
  union { unsigned int i; float f; } x; x.i = ((unsigned int)u) << 16; return x.f;
}
__device__ __forceinline__ ushort f2bf(float f) {
  union { float f; unsigned int i; } x; x.f = f;
  unsigned int lsb = (x.i >> 16) & 1u;
  unsigned int r = x.i + 0x7fffu + lsb;
  return (ushort)(r >> 16);
}

// ---------------- fp8 e4m3fn helpers (HW converts; guarded SW fallback) ----------------
__device__ __forceinline__ float dec_e4m3_sw(unsigned int b) {
  unsigned int s = b >> 7, e = (b >> 3) & 15, m = b & 7;
  float v = (e == 0) ? (float)m * 0.001953125f  // m * 2^-9
                     : (float)(8 + m) * 0.125f * exp2f((float)((int)e - 7));
  return s ? -v : v;
}
__device__ __forceinline__ unsigned char enc_e4m3_sw(float f) {
  union { float f; unsigned int u; } x; x.f = f;
  unsigned int s = (x.u >> 31) << 7;
  float a = fabsf(f);
  if (!(a > 0.f)) return (unsigned char)s;
  if (a > 448.f) a = 448.f;
  int e = 0; float mant = frexpf(a, &e);  // a = mant*2^e, mant in [0.5,1)
  int E = e + 6;
  unsigned int out;
  if (E <= 0) {
    int m = (int)rintf(a * 512.f);
    out = (m > 7) ? (s | (1u << 3)) : (s | (unsigned)m);
  } else {
    int m = (int)rintf(mant * 16.f);      // [8,16]
    if (m == 16) { m = 8; E++; }
    if (E > 15 || (E == 15 && m - 8 > 6)) { E = 15; m = 14; }  // clamp at 448
    out = s | ((unsigned)E << 3) | (unsigned)(m - 8);
  }
  return (unsigned char)out;
}
// decode 2 fp8 from low/high half of a dword; HI must be compile-time (builtin
// requires an immediate word-select -> template parameter).
template <bool HI>
__device__ __forceinline__ f32x2 fp8x2_f32(unsigned int w) {
#if __has_builtin(__builtin_amdgcn_cvt_pk_f32_fp8)
  return __builtin_amdgcn_cvt_pk_f32_fp8(w, HI);
#else
  unsigned int b0 = HI ? ((w >> 16) & 0xffu) : (w & 0xffu);
  unsigned int b1 = HI ? (w >> 24) : ((w >> 8) & 0xffu);
  f32x2 r; r[0] = dec_e4m3_sw(b0); r[1] = dec_e4m3_sw(b1); return r;
#endif
}
__device__ __forceinline__ unsigned char f32_fp8(float f) {
#if __has_builtin(__builtin_amdgcn_cvt_pk_fp8_f32)
  return (unsigned char)(__builtin_amdgcn_cvt_pk_fp8_f32(f, f, 0, false) & 0xff);
#else
  return enc_e4m3_sw(f);
#endif
}

// fast gelu (tanh form): max err ~2e-4 where pre-acts live (sigma~0.32).
__device__ __forceinline__ float fast_gelu(float t) {
  float u = 0.7978845608028654f * (t + 0.044715f * t * t * t);
  float ez = __expf(2.f * u);
  float th = 1.f - 2.f * __builtin_amdgcn_rcpf(ez + 1.f);
  return 0.5f * t * (1.f + th);
}

// async global->LDS, 16B per lane; LDS dest = wave-uniform base + lane*16.
__device__ __forceinline__ void gload_lds16(const ushort* g, ushort* l) {
  __builtin_amdgcn_global_load_lds((const __attribute__((address_space(1))) unsigned int*)g,
                                   (__attribute__((address_space(3))) unsigned int*)l,
                                   16, 0, 0);
}

// ---------------- casts fp32 -> bf16 (vectorized) ----------------
__global__ void k_cast4(const float4* __restrict__ s, ushort4* __restrict__ d, int n4) {
  int i = blockIdx.x * blockDim.x + threadIdx.x;
  if (i < n4) {
    float4 v = s[i];
    ushort4 o;
    o.x = f2bf(v.x); o.y = f2bf(v.y); o.z = f2bf(v.z); o.w = f2bf(v.w);
    d[i] = o;
  }
}

// ---------------- CSR build ----------------
__global__ void k_hist(const int* __restrict__ dst, int E, int* __restrict__ deg) {
  int i = blockIdx.x * blockDim.x + threadIdx.x;
  if (i < E) atomicAdd(&deg[dst[i]], 1);
}

__global__ __launch_bounds__(1024) void k_scan1(const int* __restrict__ deg, int N,
                                                int* __restrict__ rowptr, int* __restrict__ bsum) {
  __shared__ int s[1024];
  int t = threadIdx.x;
  int i = blockIdx.x * 1024 + t;
  int val = (i < N) ? deg[i] : 0;
  s[t] = val;
  __syncthreads();
  for (int off = 1; off < 1024; off <<= 1) {
    int add = (t >= off) ? s[t - off] : 0;
    __syncthreads();
    s[t] += add;
    __syncthreads();
  }
  if (i < N) rowptr[i + 1] = s[t];
  if (t == 1023) bsum[blockIdx.x] = s[t];
}

__global__ void k_scan2(int* __restrict__ bsum, int nb) {
  if (threadIdx.x == 0 && blockIdx.x == 0) {
    int run = 0;
    for (int j = 0; j < nb; ++j) { int t = bsum[j]; bsum[j] = run; run += t; }
  }
}

__global__ void k_scan3(int* __restrict__ rowptr, const int* __restrict__ bsum, int N) {
  int i = blockIdx.x * blockDim.x + threadIdx.x;
  if (i < N) rowptr[i + 1] += bsum[i >> 10];
  if (i == 0) rowptr[0] = 0;
}

__global__ void k_scatter(const int* __restrict__ src, const int* __restrict__ dst, int E,
                          const int* __restrict__ rowptr, int* __restrict__ cur,
                          int* __restrict__ csr_src) {
  int i = blockIdx.x * blockDim.x + threadIdx.x;
  if (i < E) {
    int d = dst[i];
    int pos = rowptr[d] + atomicAdd(&cur[d], 1);
    csr_src[pos] = src[i];
  }
}

// ---------------- m97-style staged 128x128 GEMM core ----------------
// Stage one 128x32 bf16 tile (8 KB) into LDS via global_load_lds(16B).
// Swizzle: LDS granule (row, slot) holds src granule (row, slot^(row&3)) —
// involution on SOURCE address here and on the READ below (G21).
__device__ __forceinline__ void stage_tile(const ushort* __restrict__ S, int ld,
                                           int r0, int nr, int k0,
                                           ushort* lds, int wave, int lane) {
#pragma unroll
  for (int j = 0; j < 2; ++j) {
    int g = wave * 128 + j * 64 + lane;   // granule 0..511
    int row = g >> 2, slot = g & 3;
    int rr = r0 + row; rr = (rr < nr) ? rr : (nr - 1);
    const ushort* src = S + (size_t)rr * ld + k0 + ((slot ^ (row & 3)) << 3);
    gload_lds16(src, &lds[(size_t)(wave * 128 + j * 64) * 8]);
  }
}

// K-loop: 2 barriers per BK=32 step (m97 pattern); acc = 16 f32x4 per wave.
__device__ __forceinline__ void gemm128_core(const ushort* __restrict__ A, int lda, int rowt, int nA,
                                             const ushort* __restrict__ B, int ldb, int colt, int nB,
                                             int K, ushort* lA, ushort* lB, f32x4* acc) {
  int tid = threadIdx.x;
  int wave = tid >> 6, lane = tid & 63;
  int m = lane & 15, quad = lane >> 4;
  int r0w = (wave & 1) * 64, c0w = (wave >> 1) * 64;
  int sw = (quad ^ (m & 3)) << 3;  // swizzled 16B slot (in ushorts)

  for (int k0 = 0; k0 < K; k0 += 32) {
    __syncthreads();  // prior step's LDS reads complete before overwrite
    stage_tile(A, lda, rowt, nA, k0, lA, wave, lane);
    stage_tile(B, ldb, colt, nB, k0, lB, wave, lane);
    __syncthreads();  // vmcnt(0) drained before barrier -> tiles ready

    bf8 a[4], b[4];
#pragma unroll
    for (int ri = 0; ri < 4; ++ri)
      a[ri] = *(const bf8*)&lA[(r0w + ri * 16 + m) * 32 + sw];
#pragma unroll
    for (int cj = 0; cj < 4; ++cj)
      b[cj] = *(const bf8*)&lB[(c0w + cj * 16 + m) * 32 + sw];
#pragma unroll
    for (int ri = 0; ri < 4; ++ri)
#pragma unroll
      for (int cj = 0; cj < 4; ++cj)
        acc[ri * 4 + cj] = __builtin_amdgcn_mfma_f32_16x16x32_bf16(a[ri], b[cj], acc[ri * 4 + cj], 0, 0, 0);
  }
}

// fused QKV: q (bf16) | k,v (fp8 e4m3 planes). Grid (391, 6).
// Wqkv rows 0-255 = Wq, 256-511 = Wk, 512-767 = Wv (contiguous casts).
__global__ __launch_bounds__(256) void k_qkvf(const ushort* __restrict__ featb,
                                              const ushort* __restrict__ Wqkv,
                                              const float* __restrict__ bq, const float* __restrict__ bk,
                                              const float* __restrict__ bv,
                                              ushort* __restrict__ q,
                                              unsigned char* __restrict__ k8,
                                              unsigned char* __restrict__ v8, int N) {
  __shared__ ushort lA[128 * 32];
  __shared__ ushort lB[128 * 32];
  int rowt = blockIdx.x * 128, colt = blockIdx.y * 128;
  int which = colt >> 8;  // 0=q,1=k,2=v (128-tile never straddles a 256 group)
  const float* bias = (which == 0) ? bq : (which == 1) ? bk : bv;
  int tid = threadIdx.x;
  int wave = tid >> 6, lane = tid & 63, m = lane & 15, quad = lane >> 4;
  int r0w = (wave & 1) * 64, c0w = (wave >> 1) * 64;

  f32x4 acc[16];
#pragma unroll
  for (int j = 0; j < 16; ++j) acc[j] = (f32x4){0.f, 0.f, 0.f, 0.f};

  gemm128_core(featb, CDIM, rowt, N, Wqkv, CDIM, colt, 768, CDIM, lA, lB, acc);

  unsigned char* o8 = (which == 1) ? k8 : v8;
#pragma unroll
  for (int cj = 0; cj < 4; ++cj) {
    int col = (colt + c0w + cj * 16 + m) & 255;
    float bs = bias[col];
#pragma unroll
    for (int ri = 0; ri < 4; ++ri)
#pragma unroll
      for (int i = 0; i < 4; ++i) {
        int r = rowt + r0w + ri * 16 + quad * 4 + i;
        if (r < N) {
          float vv = acc[ri * 4 + cj][i] + bs;
          if (which == 0) q[(size_t)r * CDIM + col] = f2bf(vv);
          else            o8[(size_t)r * CDIM + col] = f32_fp8(vv);
        }
      }
  }
}

// x = feat + wv @ Wp^T + bp  (fp32 out); staged core. Grid (391, 2).
__global__ __launch_bounds__(256) void k_proj(const ushort* __restrict__ wv,
                                              const ushort* __restrict__ Wp,
                                              const float* __restrict__ bp,
                                              const float* __restrict__ feat,
                                              float* __restrict__ x, int N) {
  __shared__ ushort lA[128 * 32];
  __shared__ ushort lB[128 * 32];
  int rowt = blockIdx.x * 128, colt = blockIdx.y * 128;
  int tid = threadIdx.x;
  int wave = tid >> 6, lane = tid & 63, m = lane & 15, quad = lane >> 4;
  int r0w = (wave & 1) * 64, c0w = (wave >> 1) * 64;

  f32x4 acc[16];
#pragma unroll
  for (int j = 0; j < 16; ++j) acc[j] = (f32x4){0.f, 0.f, 0.f, 0.f};

  gemm128_core(wv, CDIM, rowt, N, Wp, CDIM, colt, 256, CDIM, lA, lB, acc);

#pragma unroll
  for (int cj = 0; cj < 4; ++cj) {
    int col = colt + c0w + cj * 16 + m;
    float bs = bp[col];
#pragma unroll
    for (int ri = 0; ri < 4; ++ri)
#pragma unroll
      for (int i = 0; i < 4; ++i) {
        int r = rowt + r0w + ri * 16 + quad * 4 + i;
        if (r < N)
          x[(size_t)r * CDIM + col] = acc[ri * 4 + cj][i] + bs + feat[(size_t)r * CDIM + col];
      }
  }
}

// hidden-chunk GEMM: hid[.,0..512) = gelu(h @ W1c^T + b1c). Grid (391, 4).
__global__ __launch_bounds__(256) void k_g1(const ushort* __restrict__ h,
                                            const ushort* __restrict__ W1c,
                                            const float* __restrict__ b1c,
                                            ushort* __restrict__ hid, int N) {
  __shared__ ushort lA[128 * 32];
  __shared__ ushort lB[128 * 32];
  int rowt = blockIdx.x * 128, colt = blockIdx.y * 128;
  int tid = threadIdx.x;
  int wave = tid >> 6, lane = tid & 63, m = lane & 15, quad = lane >> 4;
  int r0w = (wave & 1) * 64, c0w = (wave >> 1) * 64;

  f32x4 acc[16];
#pragma unroll
  for (int j = 0; j < 16; ++j) acc[j] = (f32x4){0.f, 0.f, 0.f, 0.f};

  gemm128_core(h, CDIM, rowt, N, W1c, CDIM, colt, 512, CDIM, lA, lB, acc);

#pragma unroll
  for (int cj = 0; cj < 4; ++cj) {
    int col = colt + c0w + cj * 16 + m;  // hidden-local col, < 512
    float bs = b1c[col];
#pragma unroll
    for (int ri = 0; ri < 4; ++ri)
#pragma unroll
      for (int i = 0; i < 4; ++i) {
        int r = rowt + r0w + ri * 16 + quad * 4 + i;
        if (r < N) hid[(size_t)r * 512 + col] = f2bf(fast_gelu(acc[ri * 4 + cj][i] + bs));
      }
  }
}

// out-chunk GEMM: out += hid @ W2c^T (+ b2 on first pass). Grid (391, 2).
__global__ __launch_bounds__(256) void k_g2(const ushort* __restrict__ hid,
                                            const ushort* __restrict__ W2c,
                                            const float* __restrict__ b2,
                                            float* __restrict__ out, int N, int first) {
  __shared__ ushort lA[128 * 32];
  __shared__ ushort lB[128 * 32];
  int rowt = blockIdx.x * 128, colt = blockIdx.y * 128;
  int tid = threadIdx.x;
  int wave = tid >> 6, lane = tid & 63, m = lane & 15, quad = lane >> 4;
  int r0w = (wave & 1) * 64, c0w = (wave >> 1) * 64;

  f32x4 acc[16];
#pragma unroll
  for (int j = 0; j < 16; ++j) acc[j] = (f32x4){0.f, 0.f, 0.f, 0.f};

  gemm128_core(hid, 512, rowt, N, W2c, 1024, colt, 256, 512, lA, lB, acc);

#pragma unroll
  for (int cj = 0; cj < 4; ++cj) {
    int col = colt + c0w + cj * 16 + m;  // < 256
    float bs = first ? b2[col] : 0.f;
#pragma unroll
    for (int ri = 0; ri < 4; ++ri)
#pragma unroll
      for (int i = 0; i < 4; ++i) {
        int r = rowt + r0w + ri * 16 + quad * 4 + i;
        if (r < N) {
          size_t idx = (size_t)r * CDIM + col;
          out[idx] = out[idx] + acc[ri * 4 + cj][i] + bs;
        }
      }
  }
}

// fused segment softmax + aggregate, wave-per-dst, barrier-free, fp8 K/V.
// Dot phase: el=lane>>3 edge-slot, h=lane&7 head. Agg phase: lane owns 4 channels.
__global__ __launch_bounds__(256) void k_edge_agg(const ushort* __restrict__ q,
                                                  const unsigned char* __restrict__ kk8,
                                                  const unsigned char* __restrict__ vv8,
                                                  const int* __restrict__ rowptr,
                                                  const int* __restrict__ csr_src,
                                                  int N,
                                                  ushort* __restrict__ wv) {
  int wave = threadIdx.x >> 6, lane = threadIdx.x & 63;
  int n = blockIdx.x * 4 + wave;
  if (n >= N) return;  // wave-uniform; no barriers in this kernel

  int el = lane >> 3, h = lane & 7;
  int beg = rowptr[n], end = rowptr[n + 1];
  int deg = end - beg;

  // q slice for head h into registers (f32)
  float qf[32];
  {
    const ushort* qp = q + (size_t)n * CDIM + h * HDIM;
#pragma unroll
    for (int g = 0; g < 4; ++g) {
      bf8 qv = *(const bf8*)(qp + g * 8);
#pragma unroll
      for (int j = 0; j < 8; ++j) qf[g * 8 + j] = bf2f((ushort)qv[j]);
    }
  }

  float accv[4] = {0.f, 0.f, 0.f, 0.f};
  float den_part = 0.f;

  for (int c0 = 0; c0 < deg; c0 += 8) {
    int src = 0;
    float e = 0.f;
    if (c0 + el < deg) {
      src = csr_src[beg + c0 + el];
      const unsigned char* kp = kk8 + (size_t)src * CDIM + h * HDIM;  // 32B, 16B-aligned
      uint4 w0 = *(const uint4*)kp;
      uint4 w1 = *(const uint4*)(kp + 16);
      unsigned int ws[8] = {w0.x, w0.y, w0.z, w0.w, w1.x, w1.y, w1.z, w1.w};
      float dot = 0.f;
#pragma unroll
      for (int j = 0; j < 8; ++j) {
        f32x2 lo = fp8x2_f32<false>(ws[j]);
        f32x2 hi = fp8x2_f32<true>(ws[j]);
        dot = fmaf(qf[j * 4 + 0], lo[0], dot);
        dot = fmaf(qf[j * 4 + 1], lo[1], dot);
        dot = fmaf(qf[j * 4 + 2], hi[0], dot);
        dot = fmaf(qf[j * 4 + 3], hi[1], dot);
      }
      float s = dot * 0.17677669529663687f;  // 1/sqrt(32)
      s = fminf(10.f, fmaxf(-10.f, s));
      e = __expf(s - 10.f);  // fixed shift: scores clamped, softmax shift-invariant
    }
    den_part += e;

    // aggregate these 8 edges: lane reads its 4 channels of V[src_j], weight e_j[head]
#pragma unroll
    for (int j = 0; j < 8; ++j) {
      int sj = __shfl(src, j << 3);
      float ej = __shfl(e, (j << 3) | (lane >> 3));
      unsigned int vw = *(const unsigned int*)(vv8 + (size_t)sj * CDIM + lane * 4);
      f32x2 lo = fp8x2_f32<false>(vw);
      f32x2 hi = fp8x2_f32<true>(vw);
      accv[0] = fmaf(ej, lo[0], accv[0]);
      accv[1] = fmaf(ej, lo[1], accv[1]);
      accv[2] = fmaf(ej, hi[0], accv[2]);
      accv[3] = fmaf(ej, hi[1], accv[3]);
    }
  }

  // den[h] = sum over el lanes (xor over bits 3..5), broadcast to channel lanes
  float den = den_part;
  den += __shfl_xor(den, 8);
  den += __shfl_xor(den, 16);
  den += __shfl_xor(den, 32);
  float denh = __shfl(den, lane >> 3);

  float inv = (deg > 0) ? (1.f / denh) : 0.f;
  ushort4 o;
  o.x = f2bf(accv[0] * inv);
  o.y = f2bf(accv[1] * inv);
  o.z = f2bf(accv[2] * inv);
  o.w = f2bf(accv[3] * inv);
  *(ushort4*)(wv + (size_t)n * CDIM + lane * 4) = o;
}

// h = layernorm(x)*g + b -> bf16 ; ALSO copies x into out (residual base),
// freeing the x region for the hidden-chunk buffer.
__global__ __launch_bounds__(256) void k_ln(const float* __restrict__ x,
                                            const float* __restrict__ g,
                                            const float* __restrict__ b,
                                            ushort* __restrict__ h,
                                            float* __restrict__ out) {
  int row = blockIdx.x * 4 + (threadIdx.x >> 6);
  int lane = threadIdx.x & 63;
  const float* xr = x + (size_t)row * CDIM;
  float4 xv = *(const float4*)(xr + lane * 4);
  *(float4*)(out + (size_t)row * CDIM + lane * 4) = xv;  // out = x
  float s = xv.x + xv.y + xv.z + xv.w;
  float ss = xv.x * xv.x + xv.y * xv.y + xv.z * xv.z + xv.w * xv.w;
#pragma unroll
  for (int msk = 1; msk <= 32; msk <<= 1) {
    s += __shfl_xor(s, msk);
    ss += __shfl_xor(ss, msk);
  }
  float mu = s * (1.f / CDIM);
  float var = ss * (1.f / CDIM) - mu * mu;
  float rs = rsqrtf(var + 1e-5f);
  float xe[4] = {xv.x, xv.y, xv.z, xv.w};
#pragma unroll
  for (int t = 0; t < 4; ++t) {
    int cc = lane * 4 + t;
    h[(size_t)row * CDIM + cc] = f2bf((xe[t] - mu) * rs * g[cc] + b[cc]);
  }
}

extern "C" void kernel_launch(void* const* d_in, const int* in_sizes, int n_in,
                              void* d_out, int out_size, void* d_ws, size_t ws_size,
                              hipStream_t stream) {
  const float* feat = (const float*)d_in[0];
  const int* esrc = (const int*)d_in[1];
  const int* edst = (const int*)d_in[2];
  const float* Wq = (const float*)d_in[3];
  const float* bq = (const float*)d_in[4];
  const float* Wk = (const float*)d_in[5];
  const float* bk = (const float*)d_in[6];
  const float* Wv = (const float*)d_in[7];
  const float* bv = (const float*)d_in[8];
  const float* Wp = (const float*)d_in[9];
  const float* bp = (const float*)d_in[10];
  const float* lng = (const float*)d_in[11];
  const float* lnb = (const float*)d_in[12];
  const float* W1 = (const float*)d_in[13];
  const float* b1 = (const float*)d_in[14];
  const float* W2 = (const float*)d_in[15];
  const float* b2 = (const float*)d_in[16];

  const int N = in_sizes[0] / CDIM;  // 50000
  const int E = in_sizes[1];         // 1600000
  const size_t NC2 = (size_t)N * CDIM * 2;  // bf16 plane: 25.6 MB
  const size_t NC1 = (size_t)N * CDIM;      // fp8 plane: 12.8 MB

  // Workspace layout (lifetime overlays):
  //   [0,NC2) q | x(f32, 2*NC2) overlays q+k8/v8 from proj on | hid overlays x after ln
  //   [NC2,2NC2) k8 (fp8) + v8 (fp8), each NC1 — dead before x is written
  //   [2NC2,3NC2) (free) | h(bf16) from ln on
  //   [3NC2,4NC2) wv | featb(bf16) overlays (disjoint lifetime)
  //   [4NC2,..) CSR, then bf16 weights (Wq,Wk,Wv contiguous = fused Wqkv)
  char* w = (char*)d_ws;
  ushort* q   = (ushort*)(w);
  unsigned char* k8 = (unsigned char*)(w + NC2);
  unsigned char* v8 = (unsigned char*)(w + NC2 + NC1);
  ushort* wvb = (ushort*)(w + 3 * NC2);
  ushort* featb = (ushort*)(w + 3 * NC2);
  float*  x   = (float*)(w);               // overlays q+k8+v8
  ushort* h   = (ushort*)(w + 2 * NC2);
  ushort* hid = (ushort*)(w);              // overlays x (dead after k_ln)

  char* csr = w + 4 * NC2;
  int* rowptr  = (int*)(csr);
  int* deg     = (int*)(csr + 200064);
  int* csr_src = (int*)(csr + 400128);
  int* bsum    = (int*)(csr + 400128 + (size_t)E * 4);

  char* wb = csr + 400128 + (size_t)E * 4 + 256;
  ushort* Wqb = (ushort*)(wb);
  ushort* Wkb = (ushort*)(wb + 131072);
  ushort* Wvb = (ushort*)(wb + 262144);
  ushort* Wpb = (ushort*)(wb + 393216);
  ushort* W1b = (ushort*)(wb + 524288);
  ushort* W2b = (ushort*)(wb + 1048576);

  const int nb = (N + 1023) / 1024;
  const int RT128 = (N + 127) / 128; // 391

  // weight + feat casts (Wq/Wk/Wv land contiguously -> fused Wqkv matrix)
  k_cast4<<<(16384 + 255) / 256, 256, 0, stream>>>((const float4*)Wq, (ushort4*)Wqb, 16384);
  k_cast4<<<(16384 + 255) / 256, 256, 0, stream>>>((const float4*)Wk, (ushort4*)Wkb, 16384);
  k_cast4<<<(16384 + 255) / 256, 256, 0, stream>>>((const float4*)Wv, (ushort4*)Wvb, 16384);
  k_cast4<<<(16384 + 255) / 256, 256, 0, stream>>>((const float4*)Wp, (ushort4*)Wpb, 16384);
  k_cast4<<<(65536 + 255) / 256, 256, 0, stream>>>((const float4*)W1, (ushort4*)W1b, 65536);
  k_cast4<<<(65536 + 255) / 256, 256, 0, stream>>>((const float4*)W2, (ushort4*)W2b, 65536);
  {
    int n4 = N * CDIM / 4;
    k_cast4<<<(n4 + 255) / 256, 256, 0, stream>>>((const float4*)feat, (ushort4*)featb, n4);
  }

  // CSR build (group edges by dst)
  hipMemsetAsync(deg, 0, (size_t)N * 4, stream);
  k_hist<<<(E + 255) / 256, 256, 0, stream>>>(edst, E, deg);
  k_scan1<<<nb, 1024, 0, stream>>>(deg, N, rowptr, bsum);
  k_scan2<<<1, 64, 0, stream>>>(bsum, nb);
  k_scan3<<<(N + 255) / 256, 256, 0, stream>>>(rowptr, bsum, N);
  hipMemsetAsync(deg, 0, (size_t)N * 4, stream);
  k_scatter<<<(E + 255) / 256, 256, 0, stream>>>(esrc, edst, E, rowptr, deg, csr_src);

  // fused QKV projection (q bf16; k/v fp8 planes)
  k_qkvf<<<dim3(RT128, 6), 256, 0, stream>>>(featb, Wqb, bq, bk, bv, q, k8, v8, N);
  // fused segment-softmax + aggregate (wave-per-dst, barrier-free, fp8 gathers)
  k_edge_agg<<<(N + 3) / 4, 256, 0, stream>>>(q, k8, v8, rowptr, csr_src, N, wvb);
  // x = feat + wv@Wp^T + bp (staged core)
  k_proj<<<dim3(RT128, 2), 256, 0, stream>>>(wvb, Wpb, bp, feat, x, N);
  // h = LN(x); out = x (residual base; x region then free for hid)
  k_ln<<<N / 4, 256, 0, stream>>>(x, lng, lnb, h, (float*)d_out);

  // MLP: hidden in 2 passes of 512 cols; staged 128x128 GEMMs.
  for (int c = 0; c < 2; ++c) {
    k_g1<<<dim3(RT128, 4), 256, 0, stream>>>(h, W1b + (size_t)c * 512 * CDIM,
                                             b1 + c * 512, hid, N);
    k_g2<<<dim3(RT128, 2), 256, 0, stream>>>(hid, W2b + (size_t)c * 512,
                                             b2, (float*)d_out, N, c == 0 ? 1 : 0);
  }
}

// Round 9
// 720.816 us; speedup vs baseline: 1.4141x; 1.0829x over previous
//
#include <hip/hip_runtime.h>
#include <hip/hip_bf16.h>

#define CDIM 256
#define NH 8
#define HDIM 32

typedef short bf8 __attribute__((ext_vector_type(8)));
typedef float f32x4 __attribute__((ext_vector_type(4)));
typedef float f32x2 __attribute__((ext_vector_type(2)));

__device__ __forceinline__ float bf2f(ushort u) {
  union { unsigned int i; float f; } x; x.i = ((unsigned int)u) << 16; return x.f;
}
__device__ __forceinline__ ushort f2bf(float f) {
  union { float f; unsigned int i; } x; x.f = f;
  unsigned int lsb = (x.i >> 16) & 1u;
  unsigned int r = x.i + 0x7fffu + lsb;
  return (ushort)(r >> 16);
}

// ---------------- fp8 e4m3fn helpers (HW converts; guarded SW fallback) ----------------
__device__ __forceinline__ float dec_e4m3_sw(unsigned int b) {
  unsigned int s = b >> 7, e = (b >> 3) & 15, m = b & 7;
  float v = (e == 0) ? (float)m * 0.001953125f
                     : (float)(8 + m) * 0.125f * exp2f((float)((int)e - 7));
  return s ? -v : v;
}
__device__ __forceinline__ unsigned char enc_e4m3_sw(float f) {
  union { float f; unsigned int u; } x; x.f = f;
  unsigned int s = (x.u >> 31) << 7;
  float a = fabsf(f);
  if (!(a > 0.f)) return (unsigned char)s;
  if (a > 448.f) a = 448.f;
  int e = 0; float mant = frexpf(a, &e);
  int E = e + 6;
  unsigned int out;
  if (E <= 0) {
    int m = (int)rintf(a * 512.f);
    out = (m > 7) ? (s | (1u << 3)) : (s | (unsigned)m);
  } else {
    int m = (int)rintf(mant * 16.f);
    if (m == 16) { m = 8; E++; }
    if (E > 15 || (E == 15 && m - 8 > 6)) { E = 15; m = 14; }
    out = s | ((unsigned)E << 3) | (unsigned)(m - 8);
  }
  return (unsigned char)out;
}
template <bool HI>
__device__ __forceinline__ f32x2 fp8x2_f32(unsigned int w) {
#if __has_builtin(__builtin_amdgcn_cvt_pk_f32_fp8)
  return __builtin_amdgcn_cvt_pk_f32_fp8(w, HI);
#else
  unsigned int b0 = HI ? ((w >> 16) & 0xffu) : (w & 0xffu);
  unsigned int b1 = HI ? (w >> 24) : ((w >> 8) & 0xffu);
  f32x2 r; r[0] = dec_e4m3_sw(b0); r[1] = dec_e4m3_sw(b1); return r;
#endif
}
__device__ __forceinline__ unsigned char f32_fp8(float f) {
#if __has_builtin(__builtin_amdgcn_cvt_pk_fp8_f32)
  return (unsigned char)(__builtin_amdgcn_cvt_pk_fp8_f32(f, f, 0, false) & 0xff);
#else
  return enc_e4m3_sw(f);
#endif
}

// fast gelu (tanh form): max err ~2e-4 where pre-acts live (sigma~0.32).
__device__ __forceinline__ float fast_gelu(float t) {
  float u = 0.7978845608028654f * (t + 0.044715f * t * t * t);
  float ez = __expf(2.f * u);
  float th = 1.f - 2.f * __builtin_amdgcn_rcpf(ez + 1.f);
  return 0.5f * t * (1.f + th);
}

// async global->LDS, 16B per lane; LDS dest = wave-uniform base + lane*16.
__device__ __forceinline__ void gload_lds16(const ushort* g, ushort* l) {
  __builtin_amdgcn_global_load_lds((const __attribute__((address_space(1))) unsigned int*)g,
                                   (__attribute__((address_space(3))) unsigned int*)l,
                                   16, 0, 0);
}

// ---------------- casts fp32 -> bf16 (vectorized) ----------------
__global__ void k_cast4(const float4* __restrict__ s, ushort4* __restrict__ d, int n4) {
  int i = blockIdx.x * blockDim.x + threadIdx.x;
  if (i < n4) {
    float4 v = s[i];
    ushort4 o;
    o.x = f2bf(v.x); o.y = f2bf(v.y); o.z = f2bf(v.z); o.w = f2bf(v.w);
    d[i] = o;
  }
}

// ---------------- CSR build ----------------
__global__ void k_hist(const int* __restrict__ dst, int E, int* __restrict__ deg) {
  int i = blockIdx.x * blockDim.x + threadIdx.x;
  if (i < E) atomicAdd(&deg[dst[i]], 1);
}

__global__ __launch_bounds__(1024) void k_scan1(const int* __restrict__ deg, int N,
                                                int* __restrict__ rowptr, int* __restrict__ bsum) {
  __shared__ int s[1024];
  int t = threadIdx.x;
  int i = blockIdx.x * 1024 + t;
  int val = (i < N) ? deg[i] : 0;
  s[t] = val;
  __syncthreads();
  for (int off = 1; off < 1024; off <<= 1) {
    int add = (t >= off) ? s[t - off] : 0;
    __syncthreads();
    s[t] += add;
    __syncthreads();
  }
  if (i < N) rowptr[i + 1] = s[t];
  if (t == 1023) bsum[blockIdx.x] = s[t];
}

__global__ void k_scan2(int* __restrict__ bsum, int nb) {
  if (threadIdx.x == 0 && blockIdx.x == 0) {
    int run = 0;
    for (int j = 0; j < nb; ++j) { int t = bsum[j]; bsum[j] = run; run += t; }
  }
}

__global__ void k_scan3(int* __restrict__ rowptr, const int* __restrict__ bsum, int N) {
  int i = blockIdx.x * blockDim.x + threadIdx.x;
  if (i < N) rowptr[i + 1] += bsum[i >> 10];
  if (i == 0) rowptr[0] = 0;
}

__global__ void k_scatter(const int* __restrict__ src, const int* __restrict__ dst, int E,
                          const int* __restrict__ rowptr, int* __restrict__ cur,
                          int* __restrict__ csr_src) {
  int i = blockIdx.x * blockDim.x + threadIdx.x;
  if (i < E) {
    int d = dst[i];
    int pos = rowptr[d] + atomicAdd(&cur[d], 1);
    csr_src[pos] = src[i];
  }
}

// ---------------- staged 128x256 GEMM core (512 threads / 8 waves) ----------------
// A tile 128x32 (8 KB) + B tile 256x32 (16 KB) staged via global_load_lds(16B).
// Swizzle: LDS granule (row, slot) holds src granule (row, slot^(row&3)) —
// involution on SOURCE address here and on the READ below (G21).
// 256-col blocks halve the A-panel re-read factor vs 128-col blocks.
__device__ __forceinline__ void stageA8(const ushort* __restrict__ S, int ld,
                                        int r0, int nr, int k0,
                                        ushort* lds, int wave, int lane) {
  int g = wave * 64 + lane;           // granule 0..511 (128 rows x 4 slots)
  int row = g >> 2, slot = g & 3;
  int rr = r0 + row; rr = (rr < nr) ? rr : (nr - 1);
  const ushort* src = S + (size_t)rr * ld + k0 + ((slot ^ (row & 3)) << 3);
  gload_lds16(src, &lds[(size_t)(wave * 64) * 8]);
}

__device__ __forceinline__ void stageB8(const ushort* __restrict__ S, int ld,
                                        int r0, int nr, int k0,
                                        ushort* lds, int wave, int lane) {
#pragma unroll
  for (int j = 0; j < 2; ++j) {
    int g = wave * 128 + j * 64 + lane;  // granule 0..1023 (256 rows x 4 slots)
    int row = g >> 2, slot = g & 3;
    int rr = r0 + row; rr = (rr < nr) ? rr : (nr - 1);
    const ushort* src = S + (size_t)rr * ld + k0 + ((slot ^ (row & 3)) << 3);
    gload_lds16(src, &lds[(size_t)(wave * 128 + j * 64) * 8]);
  }
}

// Wave w: rows (w&1)*64, cols (w>>1)*64 of the 128x256 block tile.
__device__ __forceinline__ void gemm256_core(const ushort* __restrict__ A, int lda, int rowt, int nA,
                                             const ushort* __restrict__ B, int ldb, int colt, int nB,
                                             int K, ushort* lA, ushort* lB, f32x4* acc) {
  int tid = threadIdx.x;
  int wave = tid >> 6, lane = tid & 63;
  int m = lane & 15, quad = lane >> 4;
  int r0w = (wave & 1) * 64, c0w = (wave >> 1) * 64;
  int sw = (quad ^ (m & 3)) << 3;  // swizzled 16B slot (in ushorts)

  for (int k0 = 0; k0 < K; k0 += 32) {
    __syncthreads();  // prior step's LDS reads complete before overwrite
    stageA8(A, lda, rowt, nA, k0, lA, wave, lane);
    stageB8(B, ldb, colt, nB, k0, lB, wave, lane);
    __syncthreads();  // vmcnt(0) drained before barrier -> tiles ready

    bf8 a[4], b[4];
#pragma unroll
    for (int ri = 0; ri < 4; ++ri)
      a[ri] = *(const bf8*)&lA[(r0w + ri * 16 + m) * 32 + sw];
#pragma unroll
    for (int cj = 0; cj < 4; ++cj)
      b[cj] = *(const bf8*)&lB[(c0w + cj * 16 + m) * 32 + sw];
#pragma unroll
    for (int ri = 0; ri < 4; ++ri)
#pragma unroll
      for (int cj = 0; cj < 4; ++cj)
        acc[ri * 4 + cj] = __builtin_amdgcn_mfma_f32_16x16x32_bf16(a[ri], b[cj], acc[ri * 4 + cj], 0, 0, 0);
  }
}

// fused QKV: q (bf16) | k,v (fp8). Grid (391, 3); blockIdx.y picks q/k/v.
__global__ __launch_bounds__(512) void k_qkvf(const ushort* __restrict__ featb,
                                              const ushort* __restrict__ Wqkv,
                                              const float* __restrict__ bq, const float* __restrict__ bk,
                                              const float* __restrict__ bv,
                                              ushort* __restrict__ q,
                                              unsigned char* __restrict__ k8,
                                              unsigned char* __restrict__ v8, int N) {
  __shared__ ushort lA[128 * 32];
  __shared__ ushort lB[256 * 32];
  int rowt = blockIdx.x * 128;
  int which = blockIdx.y;
  const float* bias = (which == 0) ? bq : (which == 1) ? bk : bv;
  int tid = threadIdx.x;
  int wave = tid >> 6, lane = tid & 63, m = lane & 15, quad = lane >> 4;
  int r0w = (wave & 1) * 64, c0w = (wave >> 1) * 64;

  f32x4 acc[16];
#pragma unroll
  for (int j = 0; j < 16; ++j) acc[j] = (f32x4){0.f, 0.f, 0.f, 0.f};

  gemm256_core(featb, CDIM, rowt, N, Wqkv + (size_t)which * 256 * CDIM, CDIM, 0, 256,
               CDIM, lA, lB, acc);

  unsigned char* o8 = (which == 1) ? k8 : v8;
#pragma unroll
  for (int cj = 0; cj < 4; ++cj) {
    int col = c0w + cj * 16 + m;
    float bs = bias[col];
#pragma unroll
    for (int ri = 0; ri < 4; ++ri)
#pragma unroll
      for (int i = 0; i < 4; ++i) {
        int r = rowt + r0w + ri * 16 + quad * 4 + i;
        if (r < N) {
          float vv = acc[ri * 4 + cj][i] + bs;
          if (which == 0) q[(size_t)r * CDIM + col] = f2bf(vv);
          else            o8[(size_t)r * CDIM + col] = f32_fp8(vv);
        }
      }
  }
}

// x = feat + wv @ Wp^T + bp  (fp32 out). Grid (391).
__global__ __launch_bounds__(512) void k_proj(const ushort* __restrict__ wv,
                                              const ushort* __restrict__ Wp,
                                              const float* __restrict__ bp,
                                              const float* __restrict__ feat,
                                              float* __restrict__ x, int N) {
  __shared__ ushort lA[128 * 32];
  __shared__ ushort lB[256 * 32];
  int rowt = blockIdx.x * 128;
  int tid = threadIdx.x;
  int wave = tid >> 6, lane = tid & 63, m = lane & 15, quad = lane >> 4;
  int r0w = (wave & 1) * 64, c0w = (wave >> 1) * 64;

  f32x4 acc[16];
#pragma unroll
  for (int j = 0; j < 16; ++j) acc[j] = (f32x4){0.f, 0.f, 0.f, 0.f};

  gemm256_core(wv, CDIM, rowt, N, Wp, CDIM, 0, 256, CDIM, lA, lB, acc);

#pragma unroll
  for (int cj = 0; cj < 4; ++cj) {
    int col = c0w + cj * 16 + m;
    float bs = bp[col];
#pragma unroll
    for (int ri = 0; ri < 4; ++ri)
#pragma unroll
      for (int i = 0; i < 4; ++i) {
        int r = rowt + r0w + ri * 16 + quad * 4 + i;
        if (r < N)
          x[(size_t)r * CDIM + col] = acc[ri * 4 + cj][i] + bs + feat[(size_t)r * CDIM + col];
      }
  }
}

// hidden-chunk GEMM: hid[., colt..colt+256) = gelu(h @ W1c^T + b1c). Grid (391, 2).
__global__ __launch_bounds__(512) void k_g1(const ushort* __restrict__ h,
                                            const ushort* __restrict__ W1c,
                                            const float* __restrict__ b1c,
                                            ushort* __restrict__ hid, int N) {
  __shared__ ushort lA[128 * 32];
  __shared__ ushort lB[256 * 32];
  int rowt = blockIdx.x * 128, colt = blockIdx.y * 256;
  int tid = threadIdx.x;
  int wave = tid >> 6, lane = tid & 63, m = lane & 15, quad = lane >> 4;
  int r0w = (wave & 1) * 64, c0w = (wave >> 1) * 64;

  f32x4 acc[16];
#pragma unroll
  for (int j = 0; j < 16; ++j) acc[j] = (f32x4){0.f, 0.f, 0.f, 0.f};

  gemm256_core(h, CDIM, rowt, N, W1c, CDIM, colt, 512, CDIM, lA, lB, acc);

#pragma unroll
  for (int cj = 0; cj < 4; ++cj) {
    int col = colt + c0w + cj * 16 + m;  // hidden-local col, < 512
    float bs = b1c[col];
#pragma unroll
    for (int ri = 0; ri < 4; ++ri)
#pragma unroll
      for (int i = 0; i < 4; ++i) {
        int r = rowt + r0w + ri * 16 + quad * 4 + i;
        if (r < N) hid[(size_t)r * 512 + col] = f2bf(fast_gelu(acc[ri * 4 + cj][i] + bs));
      }
  }
}

// out-chunk GEMM: out += hid @ W2c^T (+ b2 on first pass). Grid (391).
__global__ __launch_bounds__(512) void k_g2(const ushort* __restrict__ hid,
                                            const ushort* __restrict__ W2c,
                                            const float* __restrict__ b2,
                                            float* __restrict__ out, int N, int first) {
  __shared__ ushort lA[128 * 32];
  __shared__ ushort lB[256 * 32];
  int rowt = blockIdx.x * 128;
  int tid = threadIdx.x;
  int wave = tid >> 6, lane = tid & 63, m = lane & 15, quad = lane >> 4;
  int r0w = (wave & 1) * 64, c0w = (wave >> 1) * 64;

  f32x4 acc[16];
#pragma unroll
  for (int j = 0; j < 16; ++j) acc[j] = (f32x4){0.f, 0.f, 0.f, 0.f};

  gemm256_core(hid, 512, rowt, N, W2c, 1024, 0, 256, 512, lA, lB, acc);

#pragma unroll
  for (int cj = 0; cj < 4; ++cj) {
    int col = c0w + cj * 16 + m;
    float bs = first ? b2[col] : 0.f;
#pragma unroll
    for (int ri = 0; ri < 4; ++ri)
#pragma unroll
      for (int i = 0; i < 4; ++i) {
        int r = rowt + r0w + ri * 16 + quad * 4 + i;
        if (r < N) {
          size_t idx = (size_t)r * CDIM + col;
          out[idx] = out[idx] + acc[ri * 4 + cj][i] + bs;
        }
      }
  }
}

// fused segment softmax + aggregate, wave-per-dst, barrier-free, fp8 K/V,
// one-chunk software prefetch (csr_src + K rows issued a chunk ahead, G7).
__global__ __launch_bounds__(256) void k_edge_agg(const ushort* __restrict__ q,
                                                  const unsigned char* __restrict__ kk8,
                                                  const unsigned char* __restrict__ vv8,
                                                  const int* __restrict__ rowptr,
                                                  const int* __restrict__ csr_src,
                                                  int N,
                                                  ushort* __restrict__ wv) {
  int wave = threadIdx.x >> 6, lane = threadIdx.x & 63;
  int n = blockIdx.x * 4 + wave;
  if (n >= N) return;  // wave-uniform; no barriers in this kernel

  int el = lane >> 3, h = lane & 7;
  int beg = rowptr[n], end = rowptr[n + 1];
  int deg = end - beg;

  // q slice for head h into registers (f32)
  float qf[32];
  {
    const ushort* qp = q + (size_t)n * CDIM + h * HDIM;
#pragma unroll
    for (int g = 0; g < 4; ++g) {
      bf8 qv = *(const bf8*)(qp + g * 8);
#pragma unroll
      for (int j = 0; j < 8; ++j) qf[g * 8 + j] = bf2f((ushort)qv[j]);
    }
  }

  float accv[4] = {0.f, 0.f, 0.f, 0.f};
  float den_part = 0.f;

  // prefetch chunk 0 (invalid lanes read row 0 — harmless, e forced to 0)
  int src_n = (el < deg) ? csr_src[beg + el] : 0;
  const unsigned char* kp0 = kk8 + (size_t)src_n * CDIM + h * HDIM;
  uint4 w0_n = *(const uint4*)kp0;
  uint4 w1_n = *(const uint4*)(kp0 + 16);

  for (int c0 = 0; c0 < deg; c0 += 8) {
    int src = src_n;
    uint4 w0 = w0_n, w1 = w1_n;
    bool vcur = (c0 + el < deg);

    // issue next chunk's loads before consuming this chunk (latency overlap)
    src_n = (c0 + 8 + el < deg) ? csr_src[beg + c0 + 8 + el] : 0;
    const unsigned char* kpn = kk8 + (size_t)src_n * CDIM + h * HDIM;
    w0_n = *(const uint4*)kpn;
    w1_n = *(const uint4*)(kpn + 16);

    float e = 0.f;
    if (vcur) {
      unsigned int ws[8] = {w0.x, w0.y, w0.z, w0.w, w1.x, w1.y, w1.z, w1.w};
      float dot = 0.f;
#pragma unroll
      for (int j = 0; j < 8; ++j) {
        f32x2 lo = fp8x2_f32<false>(ws[j]);
        f32x2 hi = fp8x2_f32<true>(ws[j]);
        dot = fmaf(qf[j * 4 + 0], lo[0], dot);
        dot = fmaf(qf[j * 4 + 1], lo[1], dot);
        dot = fmaf(qf[j * 4 + 2], hi[0], dot);
        dot = fmaf(qf[j * 4 + 3], hi[1], dot);
      }
      float s = dot * 0.17677669529663687f;  // 1/sqrt(32)
      s = fminf(10.f, fmaxf(-10.f, s));
      e = __expf(s - 10.f);  // fixed shift: scores clamped, softmax shift-invariant
    }
    den_part += e;

    // aggregate these 8 edges: lane reads its 4 channels of V[src_j], weight e_j[head]
#pragma unroll
    for (int j = 0; j < 8; ++j) {
      int sj = __shfl(src, j << 3);
      float ej = __shfl(e, (j << 3) | (lane >> 3));
      unsigned int vw = *(const unsigned int*)(vv8 + (size_t)sj * CDIM + lane * 4);
      f32x2 lo = fp8x2_f32<false>(vw);
      f32x2 hi = fp8x2_f32<true>(vw);
      accv[0] = fmaf(ej, lo[0], accv[0]);
      accv[1] = fmaf(ej, lo[1], accv[1]);
      accv[2] = fmaf(ej, hi[0], accv[2]);
      accv[3] = fmaf(ej, hi[1], accv[3]);
    }
  }

  // den[h] = sum over el lanes (xor over bits 3..5), broadcast to channel lanes
  float den = den_part;
  den += __shfl_xor(den, 8);
  den += __shfl_xor(den, 16);
  den += __shfl_xor(den, 32);
  float denh = __shfl(den, lane >> 3);

  float inv = (deg > 0) ? (1.f / denh) : 0.f;
  ushort4 o;
  o.x = f2bf(accv[0] * inv);
  o.y = f2bf(accv[1] * inv);
  o.z = f2bf(accv[2] * inv);
  o.w = f2bf(accv[3] * inv);
  *(ushort4*)(wv + (size_t)n * CDIM + lane * 4) = o;
}

// h = layernorm(x)*g + b -> bf16 ; ALSO copies x into out (residual base),
// freeing the x region for the hidden-chunk buffer.
__global__ __launch_bounds__(256) void k_ln(const float* __restrict__ x,
                                            const float* __restrict__ g,
                                            const float* __restrict__ b,
                                            ushort* __restrict__ h,
                                            float* __restrict__ out) {
  int row = blockIdx.x * 4 + (threadIdx.x >> 6);
  int lane = threadIdx.x & 63;
  const float* xr = x + (size_t)row * CDIM;
  float4 xv = *(const float4*)(xr + lane * 4);
  *(float4*)(out + (size_t)row * CDIM + lane * 4) = xv;  // out = x
  float s = xv.x + xv.y + xv.z + xv.w;
  float ss = xv.x * xv.x + xv.y * xv.y + xv.z * xv.z + xv.w * xv.w;
#pragma unroll
  for (int msk = 1; msk <= 32; msk <<= 1) {
    s += __shfl_xor(s, msk);
    ss += __shfl_xor(ss, msk);
  }
  float mu = s * (1.f / CDIM);
  float var = ss * (1.f / CDIM) - mu * mu;
  float rs = rsqrtf(var + 1e-5f);
  float xe[4] = {xv.x, xv.y, xv.z, xv.w};
#pragma unroll
  for (int t = 0; t < 4; ++t) {
    int cc = lane * 4 + t;
    h[(size_t)row * CDIM + cc] = f2bf((xe[t] - mu) * rs * g[cc] + b[cc]);
  }
}

extern "C" void kernel_launch(void* const* d_in, const int* in_sizes, int n_in,
                              void* d_out, int out_size, void* d_ws, size_t ws_size,
                              hipStream_t stream) {
  const float* feat = (const float*)d_in[0];
  const int* esrc = (const int*)d_in[1];
  const int* edst = (const int*)d_in[2];
  const float* Wq = (const float*)d_in[3];
  const float* bq = (const float*)d_in[4];
  const float* Wk = (const float*)d_in[5];
  const float* bk = (const float*)d_in[6];
  const float* Wv = (const float*)d_in[7];
  const float* bv = (const float*)d_in[8];
  const float* Wp = (const float*)d_in[9];
  const float* bp = (const float*)d_in[10];
  const float* lng = (const float*)d_in[11];
  const float* lnb = (const float*)d_in[12];
  const float* W1 = (const float*)d_in[13];
  const float* b1 = (const float*)d_in[14];
  const float* W2 = (const float*)d_in[15];
  const float* b2 = (const float*)d_in[16];

  const int N = in_sizes[0] / CDIM;  // 50000
  const int E = in_sizes[1];         // 1600000
  const size_t NC2 = (size_t)N * CDIM * 2;  // bf16 plane: 25.6 MB
  const size_t NC1 = (size_t)N * CDIM;      // fp8 plane: 12.8 MB

  // Workspace layout (lifetime overlays):
  //   [0,NC2) q | x(f32, 2*NC2) overlays q+k8/v8 from proj on | hid overlays x after ln
  //   [NC2,2NC2) k8 (fp8) + v8 (fp8), each NC1 — dead before x is written
  //   [2NC2,3NC2) (free) | h(bf16) from ln on
  //   [3NC2,4NC2) wv | featb(bf16) overlays (disjoint lifetime)
  //   [4NC2,..) CSR, then bf16 weights (Wq,Wk,Wv contiguous = fused Wqkv)
  char* w = (char*)d_ws;
  ushort* q   = (ushort*)(w);
  unsigned char* k8 = (unsigned char*)(w + NC2);
  unsigned char* v8 = (unsigned char*)(w + NC2 + NC1);
  ushort* wvb = (ushort*)(w + 3 * NC2);
  ushort* featb = (ushort*)(w + 3 * NC2);
  float*  x   = (float*)(w);               // overlays q+k8+v8
  ushort* h   = (ushort*)(w + 2 * NC2);
  ushort* hid = (ushort*)(w);              // overlays x (dead after k_ln)

  char* csr = w + 4 * NC2;
  int* rowptr  = (int*)(csr);
  int* deg     = (int*)(csr + 200064);
  int* csr_src = (int*)(csr + 400128);
  int* bsum    = (int*)(csr + 400128 + (size_t)E * 4);

  char* wb = csr + 400128 + (size_t)E * 4 + 256;
  ushort* Wqb = (ushort*)(wb);
  ushort* Wkb = (ushort*)(wb + 131072);
  ushort* Wvb = (ushort*)(wb + 262144);
  ushort* Wpb = (ushort*)(wb + 393216);
  ushort* W1b = (ushort*)(wb + 524288);
  ushort* W2b = (ushort*)(wb + 1048576);

  const int nb = (N + 1023) / 1024;
  const int RT128 = (N + 127) / 128; // 391

  // weight + feat casts (Wq/Wk/Wv land contiguously -> fused Wqkv matrix)
  k_cast4<<<(16384 + 255) / 256, 256, 0, stream>>>((const float4*)Wq, (ushort4*)Wqb, 16384);
  k_cast4<<<(16384 + 255) / 256, 256, 0, stream>>>((const float4*)Wk, (ushort4*)Wkb, 16384);
  k_cast4<<<(16384 + 255) / 256, 256, 0, stream>>>((const float4*)Wv, (ushort4*)Wvb, 16384);
  k_cast4<<<(16384 + 255) / 256, 256, 0, stream>>>((const float4*)Wp, (ushort4*)Wpb, 16384);
  k_cast4<<<(65536 + 255) / 256, 256, 0, stream>>>((const float4*)W1, (ushort4*)W1b, 65536);
  k_cast4<<<(65536 + 255) / 256, 256, 0, stream>>>((const float4*)W2, (ushort4*)W2b, 65536);
  {
    int n4 = N * CDIM / 4;
    k_cast4<<<(n4 + 255) / 256, 256, 0, stream>>>((const float4*)feat, (ushort4*)featb, n4);
  }

  // CSR build (group edges by dst)
  hipMemsetAsync(deg, 0, (size_t)N * 4, stream);
  k_hist<<<(E + 255) / 256, 256, 0, stream>>>(edst, E, deg);
  k_scan1<<<nb, 1024, 0, stream>>>(deg, N, rowptr, bsum);
  k_scan2<<<1, 64, 0, stream>>>(bsum, nb);
  k_scan3<<<(N + 255) / 256, 256, 0, stream>>>(rowptr, bsum, N);
  hipMemsetAsync(deg, 0, (size_t)N * 4, stream);
  k_scatter<<<(E + 255) / 256, 256, 0, stream>>>(esrc, edst, E, rowptr, deg, csr_src);

  // fused QKV projection (q bf16; k/v fp8 planes), 128x256 blocks
  k_qkvf<<<dim3(RT128, 3), 512, 0, stream>>>(featb, Wqb, bq, bk, bv, q, k8, v8, N);
  // fused segment-softmax + aggregate (wave-per-dst, prefetched fp8 gathers)
  k_edge_agg<<<(N + 3) / 4, 256, 0, stream>>>(q, k8, v8, rowptr, csr_src, N, wvb);
  // x = feat + wv@Wp^T + bp
  k_proj<<<RT128, 512, 0, stream>>>(wvb, Wpb, bp, feat, x, N);
  // h = LN(x); out = x (residual base; x region then free for hid)
  k_ln<<<N / 4, 256, 0, stream>>>(x, lng, lnb, h, (float*)d_out);

  // MLP: hidden in 2 passes of 512 cols; 128x256 staged GEMMs.
  for (int c = 0; c < 2; ++c) {
    k_g1<<<dim3(RT128, 2), 512, 0, stream>>>(h, W1b + (size_t)c * 512 * CDIM,
                                             b1 + c * 512, hid, N);
    k_g2<<<RT128, 512, 0, stream>>>(hid, W2b + (size_t)c * 512,
                                    b2, (float*)d_out, N, c == 0 ? 1 : 0);
  }
}